// Round 1
// 125.904 us; speedup vs baseline: 1.0156x; 1.0156x over previous
//
#include <hip/hip_runtime.h>
#include <math.h>

#define TT 2048
#define LK 769
#define NF 20
#define NS 128
#define NB 18
#define NFFT 4096

typedef __attribute__((ext_vector_type(8))) short short8;
typedef __attribute__((ext_vector_type(4))) float f32x4;

__device__ __forceinline__ float2 cmul(float2 a, float2 b) {
  return make_float2(a.x * b.x - a.y * b.y, a.x * b.y + a.y * b.x);
}
__device__ __forceinline__ float2 cmulc(float2 a, float2 b) {  // a * conj(b)
  return make_float2(a.x * b.x + a.y * b.y, a.y * b.x - a.x * b.y);
}
#define CADD(a, b) make_float2((a).x + (b).x, (a).y + (b).y)
#define CSUB(a, b) make_float2((a).x - (b).x, (a).y - (b).y)

// ---------------------------------------------------------------------------
// Radix-8 DIF forward stage (verbatim butterfly from the verified 2048 code,
// parameterized by (tt, Q)). Output left in base-8 digit-reversed order after
// the full stage sequence; the mirrored inverse consumes that same order.
// ---------------------------------------------------------------------------
__device__ __forceinline__ void fwd_r8(float2* z, const float2* __restrict__ tw,
                                       int tt, int Q) {
  const float C = 0.70710678118654752f;
  const int j = tt & (Q - 1);
  const int base = ((tt & ~(Q - 1)) << 3) + j;
  const float2 x0 = z[base],         x1 = z[base + Q];
  const float2 x2 = z[base + 2 * Q], x3 = z[base + 3 * Q];
  const float2 x4 = z[base + 4 * Q], x5 = z[base + 5 * Q];
  const float2 x6 = z[base + 6 * Q], x7 = z[base + 7 * Q];
  const float2 W1 = tw[4 * Q + j], W2 = tw[2 * Q + j], W4 = tw[Q + j];
  const float2 W3 = cmul(W1, W2);
  const float2 W5 = cmul(W1, W4);
  const float2 W6 = cmul(W2, W4);
  const float2 W7 = cmul(W3, W4);
  const float2 s0 = CADD(x0, x4), s1 = CSUB(x0, x4);
  const float2 s2 = CADD(x2, x6), s3 = CSUB(x2, x6);
  const float2 E0 = CADD(s0, s2), E2 = CSUB(s0, s2);
  const float2 E1 = make_float2(s1.x + s3.y, s1.y - s3.x);
  const float2 E3 = make_float2(s1.x - s3.y, s1.y + s3.x);
  const float2 t0 = CADD(x1, x5), t1 = CSUB(x1, x5);
  const float2 t2 = CADD(x3, x7), t3 = CSUB(x3, x7);
  const float2 O0 = CADD(t0, t2), O2 = CSUB(t0, t2);
  const float2 O1 = make_float2(t1.x + t3.y, t1.y - t3.x);
  const float2 O3 = make_float2(t1.x - t3.y, t1.y + t3.x);
  const float2 wO1 = make_float2(C * (O1.x + O1.y), C * (O1.y - O1.x));
  const float2 w3O3 = make_float2(C * (O3.y - O3.x), -C * (O3.x + O3.y));
  const float2 mO2 = make_float2(O2.y, -O2.x);
  const float2 y0 = CADD(E0, O0), y4 = CSUB(E0, O0);
  const float2 y1 = CADD(E1, wO1), y5 = CSUB(E1, wO1);
  const float2 y2 = CADD(E2, mO2), y6 = CSUB(E2, mO2);
  const float2 y3 = CADD(E3, w3O3), y7 = CSUB(E3, w3O3);
  z[base]         = y0;
  z[base + Q]     = cmul(y1, W1);
  z[base + 2 * Q] = cmul(y2, W2);
  z[base + 3 * Q] = cmul(y3, W3);
  z[base + 4 * Q] = cmul(y4, W4);
  z[base + 5 * Q] = cmul(y5, W5);
  z[base + 6 * Q] = cmul(y6, W6);
  z[base + 7 * Q] = cmul(y7, W7);
}

// Radix-8 inverse stage (verbatim from verified inverse code), mirror of fwd.
__device__ __forceinline__ void inv_r8(float2* z, const float2* __restrict__ tw,
                                       int tt, int Q) {
  const float C = 0.70710678118654752f;
  const int j = tt & (Q - 1);
  const int base = ((tt & ~(Q - 1)) << 3) + j;
  const float2 W1 = tw[4 * Q + j], W2 = tw[2 * Q + j], W4 = tw[Q + j];
  const float2 W3 = cmul(W1, W2);
  const float2 W5 = cmul(W1, W4);
  const float2 W6 = cmul(W2, W4);
  const float2 W7 = cmul(W3, W4);
  const float2 u0 = z[base];
  const float2 u1 = cmulc(z[base + Q], W1);
  const float2 u2 = cmulc(z[base + 2 * Q], W2);
  const float2 u3 = cmulc(z[base + 3 * Q], W3);
  const float2 u4 = cmulc(z[base + 4 * Q], W4);
  const float2 u5 = cmulc(z[base + 5 * Q], W5);
  const float2 u6 = cmulc(z[base + 6 * Q], W6);
  const float2 u7 = cmulc(z[base + 7 * Q], W7);
  const float2 s0 = CADD(u0, u4), s1 = CSUB(u0, u4);
  const float2 s2 = CADD(u2, u6), s3 = CSUB(u2, u6);
  const float2 E0 = CADD(s0, s2), E2 = CSUB(s0, s2);
  const float2 E1 = make_float2(s1.x - s3.y, s1.y + s3.x);
  const float2 E3 = make_float2(s1.x + s3.y, s1.y - s3.x);
  const float2 t0 = CADD(u1, u5), t1 = CSUB(u1, u5);
  const float2 t2 = CADD(u3, u7), t3 = CSUB(u3, u7);
  const float2 O0 = CADD(t0, t2), O2 = CSUB(t0, t2);
  const float2 O1 = make_float2(t1.x - t3.y, t1.y + t3.x);
  const float2 O3 = make_float2(t1.x + t3.y, t1.y - t3.x);
  const float2 nO1 = make_float2(C * (O1.x - O1.y), C * (O1.x + O1.y));
  const float2 n3O3 = make_float2(-C * (O3.x + O3.y), C * (O3.x - O3.y));
  const float2 iO2 = make_float2(-O2.y, O2.x);
  z[base]         = CADD(E0, O0);
  z[base + 4 * Q] = CSUB(E0, O0);
  z[base + Q]     = CADD(E1, nO1);
  z[base + 5 * Q] = CSUB(E1, nO1);
  z[base + 2 * Q] = CADD(E2, iO2);
  z[base + 6 * Q] = CSUB(E2, iO2);
  z[base + 3 * Q] = CADD(E3, n3O3);
  z[base + 7 * Q] = CSUB(E3, n3O3);
}

// ---------------------------------------------------------------------------
// Kernel P: twiddles for N up to 4096 (max index used = 2048+511) + zero out.
// ---------------------------------------------------------------------------
__global__ __launch_bounds__(256) void prep_kernel(float2* __restrict__ tw,
                                                   float* __restrict__ out) {
  const int i = blockIdx.x * 256 + threadIdx.x;   // grid 16 -> [0,4096)
  if (i == 0) {
    tw[0] = make_float2(1.f, 0.f);
  } else {
    int half = 1 << (31 - __clz(i));
    int j = i - half;
    float ang = -3.14159265358979323846f * (float)j / (float)half;
    float s, c;
    sincosf(ang, &s, &c);
    tw[i] = make_float2(c, s);
  }
  if (i < 3200) out[i] = 0.f;
}

// ---------------------------------------------------------------------------
// Kernel S: forward FFT4096 producers (digit-reversed order, kept as-is).
//   blk <  20 : symmetrized filter o=blk  -> Hc[o] = conj(H)/4096
//   blk >= 20 : reflect-padded signal n=blk-20 -> Xs[n] = X
// Linear conv window is 2048+768 = 2816 < 4096 -> circular == linear on crop.
// ---------------------------------------------------------------------------
__global__ __launch_bounds__(256) void specf_kernel(const float* __restrict__ x,
                                                    const float* __restrict__ ker,
                                                    const float2* __restrict__ tw,
                                                    float2* __restrict__ Hc,
                                                    float2* __restrict__ Xs) {
  __shared__ __align__(16) float2 z[NFFT];
  const int tid = threadIdx.x;
  const int blk = blockIdx.x;
  if (blk < NF) {
    const float* kr = ker + blk * LK;
#pragma unroll
    for (int h = 0; h < 16; ++h) {
      int i = tid + 256 * h;
      float v = 0.f;
      if (i < LK) v = 0.5f * (kr[i] + kr[LK - 1 - i]);   // symmetrize
      z[i] = make_float2(v, 0.f);
    }
  } else {
    const float* xr = x + (size_t)(blk - NF) * TT;
#pragma unroll
    for (int h = 0; h < 16; ++h) {
      int i = tid + 256 * h;
      float v = 0.f;
      if (i < 2816) {                 // window index i -> original i-384
        int m = i - 384;
        if (m < 0) m = -m;            // reflect (edge excluded)
        if (m > 2047) m = 4094 - m;
        v = xr[m];
      }
      z[i] = make_float2(v, 0.f);
    }
  }
  __syncthreads();
  // forward: Q = 512 (cross-wave), 64, 8, 1 (wave-local after first)
  fwd_r8(z, tw, tid, 512);
  fwd_r8(z, tw, tid + 256, 512);
  __syncthreads();
  fwd_r8(z, tw, tid, 64);
  fwd_r8(z, tw, tid + 256, 64);
  __builtin_amdgcn_wave_barrier();
  fwd_r8(z, tw, tid, 8);
  fwd_r8(z, tw, tid + 256, 8);
  __builtin_amdgcn_wave_barrier();
  fwd_r8(z, tw, tid, 1);
  fwd_r8(z, tw, tid + 256, 1);
  __syncthreads();
  if (blk < NF) {
    const float s = 1.0f / 4096.0f;   // fold IFFT4096 normalization into Hc
    float2* o = Hc + (size_t)blk * NFFT;
#pragma unroll
    for (int h = 0; h < 16; ++h) {
      int i = tid + 256 * h;
      float2 v = z[i];
      o[i] = make_float2(v.x * s, -v.y * s);   // conj
    }
  } else {
    float2* o = Xs + (size_t)(blk - NF) * NFFT;
#pragma unroll
    for (int h = 0; h < 16; ++h) {
      int i = tid + 256 * h;
      o[i] = z[i];
    }
  }
}

// ---------------------------------------------------------------------------
// Kernel A: frequency-domain conv + Hilbert.
// G(f) = X(f) * (conj(H1)(f) + i*conj(H2)(f))  -> IFFT4096 -> y1 + i*y2 at
// t in [0,2048) in natural order in z[0..2048) -- exactly the state the
// verified FFT2048/mask/IFFT2048/epilogue pipeline (kept verbatim) expects.
// ---------------------------------------------------------------------------
__global__ __launch_bounds__(256) void convhil_kernel(const float2* __restrict__ Xs,
                                                      const float2* __restrict__ Hc,
                                                      const float2* __restrict__ tw,
                                                      float* __restrict__ filt) {
  __shared__ __align__(16) float2 z[NFFT];   // 32 KB
  const int tid = threadIdx.x;
  const int wv = tid >> 6;
  const int lane = tid & 63;
  const int ord = blockIdx.x;
  const int p = ord / NS;
  const int n = ord % NS;
  const int o1 = p;                          // pha band
  const int o2 = 10 + (9 - p);               // amp band (short with long)
  const float2* Xn = Xs + (size_t)n * NFFT;
  const float2* H1 = Hc + (size_t)o1 * NFFT;
  const float2* H2 = Hc + (size_t)o2 * NFFT;
#pragma unroll
  for (int h = 0; h < 16; ++h) {
    int i = tid + 256 * h;
    float2 Xv = Xn[i];
    float2 a = H1[i];
    float2 b = H2[i];
    float2 Cc = make_float2(a.x - b.y, a.y + b.x);   // H1c + i*H2c
    z[i] = cmul(Xv, Cc);
  }
  __syncthreads();
  // inverse: Q = 1, 8 (wave-local), 64 (wave-local), 512 (cross-wave)
  inv_r8(z, tw, tid, 1);
  inv_r8(z, tw, tid + 256, 1);
  __builtin_amdgcn_wave_barrier();
  inv_r8(z, tw, tid, 8);
  inv_r8(z, tw, tid + 256, 8);
  __builtin_amdgcn_wave_barrier();
  inv_r8(z, tw, tid, 64);
  inv_r8(z, tw, tid + 256, 64);
  __syncthreads();
  inv_r8(z, tw, tid, 512);
  inv_r8(z, tw, tid + 256, 512);
  __syncthreads();
  // ---- grab y1,y2 into registers (same roles as old acc1*/acc2*) ----
  const int bA = 4 * tid;
  const int bB = 1024 + 4 * tid;
  float acc1A[4], acc1B[4], acc2A[4], acc2B[4];
#pragma unroll
  for (int r = 0; r < 4; ++r) {
    float2 vA = z[bA + r]; acc1A[r] = vA.x; acc2A[r] = vA.y;
    float2 vB = z[bB + r]; acc1B[r] = vB.x; acc2B[r] = vB.y;
  }
  __syncthreads();                                    // barrier 3
  const float C = 0.70710678118654752f;
  // ---- forward radix-8 stage Q=256 (cross-wave) ----
  fwd_r8(z, tw, tid, 256);
  __syncthreads();                                    // barrier 4
  // ---- forward radix-8 stages Q=32, Q=4 (wave-local) ----
  fwd_r8(z, tw, tid, 32);
  __builtin_amdgcn_wave_barrier();
  fwd_r8(z, tw, tid, 4);
  __builtin_amdgcn_wave_barrier();
  // ---- forward radix-4 stage (Q=1), wave-local: bf in [128w, 128w+128) ----
#pragma unroll
  for (int h = 0; h < 2; ++h) {
    const int bf = 128 * wv + lane + 64 * h;
    const int base = bf << 2;
    const float2 x0 = z[base], x1 = z[base + 1];
    const float2 x2 = z[base + 2], x3 = z[base + 3];
    const float2 t0 = CADD(x0, x2), t1 = CSUB(x0, x2);
    const float2 t2 = CADD(x1, x3), t3 = CSUB(x1, x3);
    z[base]     = CADD(t0, t2);
    z[base + 1] = make_float2(t1.x + t3.y, t1.y - t3.x);
    z[base + 2] = CSUB(t0, t2);
    z[base + 3] = make_float2(t1.x - t3.y, t1.y + t3.x);
  }
  __builtin_amdgcn_wave_barrier();
  // ---- Hilbert mask, wave-local: pp in [512w, 512w+512) ----
#pragma unroll
  for (int i = 0; i < 8; ++i) {
    const int pp = 512 * wv + lane + 64 * i;
    if (pp != 0 && pp != 2) {
      if (pp & 2) { z[pp] = make_float2(0.f, 0.f); }
      else        { float2 v = z[pp]; z[pp] = make_float2(2.f * v.x, 2.f * v.y); }
    }
  }
  __builtin_amdgcn_wave_barrier();
  // ---- inverse radix-4 stage (Q=1), wave-local ----
#pragma unroll
  for (int h = 0; h < 2; ++h) {
    const int bf = 128 * wv + lane + 64 * h;
    const int base = bf << 2;
    const float2 u0 = z[base], u1 = z[base + 1];
    const float2 u2 = z[base + 2], u3 = z[base + 3];
    const float2 t0 = CADD(u0, u2), t1 = CSUB(u0, u2);
    const float2 t2 = CADD(u1, u3), t3 = CSUB(u1, u3);
    z[base]     = CADD(t0, t2);
    z[base + 1] = make_float2(t1.x - t3.y, t1.y + t3.x);
    z[base + 2] = CSUB(t0, t2);
    z[base + 3] = make_float2(t1.x + t3.y, t1.y - t3.x);
  }
  __builtin_amdgcn_wave_barrier();
  // ---- inverse radix-8 stages Q=4, Q=32 (wave-local) ----
  inv_r8(z, tw, tid, 4);
  __builtin_amdgcn_wave_barrier();
  inv_r8(z, tw, tid, 32);
  __builtin_amdgcn_wave_barrier();
  __syncthreads();                                    // barrier 5
  // ---- inverse radix-8 stage Q=256 (cross-wave) ----
  inv_r8(z, tw, tid, 256);
  __syncthreads();                                    // barrier 6
  (void)C;
  // ---- epilogue: phase for o1, amp for o2; y1,y2 still in registers ----
  float* out1 = filt + ((size_t)n * NF + o1) * TT;
  float* out2 = filt + ((size_t)n * NF + o2) * TT;
  const float invN = 1.0f / 2048.0f;
  float phA[4], phB[4], amA[4], amB[4];
#pragma unroll
  for (int r = 0; r < 4; ++r) {
    float2 wvA = z[bA + r];
    float h1 = wvA.y * invN - acc2A[r];
    float h2 = acc1A[r] - wvA.x * invN;
    phA[r] = atan2f(h1, acc1A[r]);
    amA[r] = sqrtf(fmaf(acc2A[r], acc2A[r], h2 * h2));
    float2 wvB = z[bB + r];
    float g1 = wvB.y * invN - acc2B[r];
    float g2 = acc1B[r] - wvB.x * invN;
    phB[r] = atan2f(g1, acc1B[r]);
    amB[r] = sqrtf(fmaf(acc2B[r], acc2B[r], g2 * g2));
  }
  *(float4*)&out1[bA] = make_float4(phA[0], phA[1], phA[2], phA[3]);
  *(float4*)&out1[bB] = make_float4(phB[0], phB[1], phB[2], phB[3]);
  *(float4*)&out2[bA] = make_float4(amA[0], amA[1], amA[2], amA[3]);
  *(float4*)&out2[bB] = make_float4(amB[0], amB[1], amB[2], amB[3]);
}

// ---------------------------------------------------------------------------
// Kernel C: binned MI via MFMA — UNCHANGED (verified).
// ---------------------------------------------------------------------------
__global__ __launch_bounds__(256) void mi_kernel(const float* __restrict__ filt,
                                                 float* __restrict__ out) {
  __shared__ __align__(16) unsigned int idx32[512];  // 4 bins/dword
  __shared__ float Cp[4][12][19];                    // per-wave partial C
  const int tid = threadIdx.x;
  const int wave = tid >> 6;
  const int lane = tid & 63;
  const int blk = blockIdx.x;           // bc*40 + jp
  const int bc = blk / 40, jp = blk % 40;
  const float* ph = filt + ((size_t)(bc * 4 + jp / 10) * NF + (jp % 10)) * TT;
  for (int g = tid; g < 512; g += 256) {
    float4 v = *(const float4*)&ph[4 * g];
    float vv[4] = {v.x, v.y, v.z, v.w};
    unsigned int packed = 0;
#pragma unroll
    for (int j = 0; j < 4; ++j) {
      int b = (int)floorf((vv[j] + 3.14159274f) / 6.2831855f * 18.0f);
      b = b < 0 ? 0 : (b > 17 ? 17 : b);
      packed |= ((unsigned int)b) << (8 * j);
    }
    idx32[g] = packed;
  }
  __syncthreads();
  const int n16 = lane & 15;    // A row m / B col n / C col
  const int quad = lane >> 4;   // k-quad (0..3)
  const int aband = n16 < 10 ? n16 : 9;
  const int ja = (jp & 3) + 4 * aband;   // scrambled amp row, same s'
  const float* aptr = filt + ((size_t)(bc * 4 + ja / 10) * NF + 10 + (ja % 10)) * TT
                      + quad * 8;
  const bool isAmp = (n16 < 10);
  const bool isOne = (n16 == 10);
  f32x4 acc0 = {0.f, 0.f, 0.f, 0.f};     // bins 0..15
  f32x4 acc1 = {0.f, 0.f, 0.f, 0.f};     // bins 16..17 (cols 16+n16)
  const int s0 = wave * 16, s1 = s0 + 16;
  float4 p0 = *(const float4*)(aptr + s0 * 32);
  float4 p1 = *(const float4*)(aptr + s0 * 32 + 4);
  for (int s = s0; s < s1; ++s) {
    float4 c0 = p0, c1 = p1;
    if (s < s1 - 1) {
      p0 = *(const float4*)(aptr + (s + 1) * 32);
      p1 = *(const float4*)(aptr + (s + 1) * 32 + 4);
    }
    float a[8] = {c0.x, c0.y, c0.z, c0.w, c1.x, c1.y, c1.z, c1.w};
    short8 ah, am_, al;
#pragma unroll
    for (int j = 0; j < 8; ++j) {
      float v = isAmp ? a[j] : (isOne ? 1.0f : 0.0f);
      unsigned int u = __float_as_uint(v);
      float h = __uint_as_float(u & 0xFFFF0000u);
      float r1 = v - h;                       // exact (<=16 sig bits)
      unsigned int u2 = __float_as_uint(r1);
      float md = __uint_as_float(u2 & 0xFFFF0000u);
      float r2 = r1 - md;                     // exact (<=8 sig bits)
      unsigned int u3 = __float_as_uint(r2);
      ah[j] = (short)(u >> 16);
      am_[j] = (short)(u2 >> 16);
      al[j] = (short)(u3 >> 16);
    }
    const int dw = s * 8 + quad * 2;
    unsigned int d0 = idx32[dw], d1 = idx32[dw + 1];
    short8 b0, b1;
#pragma unroll
    for (int j = 0; j < 8; ++j) {
      unsigned int byte = ((j < 4 ? d0 : d1) >> ((j & 3) * 8)) & 0xFFu;
      b0[j] = (byte == (unsigned int)n16) ? (short)0x3F80 : (short)0;
      b1[j] = (byte == (unsigned int)(n16 + 16)) ? (short)0x3F80 : (short)0;
    }
    acc0 = __builtin_amdgcn_mfma_f32_16x16x32_bf16(ah, b0, acc0, 0, 0, 0);
    acc0 = __builtin_amdgcn_mfma_f32_16x16x32_bf16(am_, b0, acc0, 0, 0, 0);
    acc0 = __builtin_amdgcn_mfma_f32_16x16x32_bf16(al, b0, acc0, 0, 0, 0);
    acc1 = __builtin_amdgcn_mfma_f32_16x16x32_bf16(ah, b1, acc1, 0, 0, 0);
    acc1 = __builtin_amdgcn_mfma_f32_16x16x32_bf16(am_, b1, acc1, 0, 0, 0);
    acc1 = __builtin_amdgcn_mfma_f32_16x16x32_bf16(al, b1, acc1, 0, 0, 0);
  }
#pragma unroll
  for (int r = 0; r < 4; ++r) {
    int row = quad * 4 + r;
    if (row < 11) {
      Cp[wave][row][n16] = acc0[r];
      if (n16 < 2) Cp[wave][row][16 + n16] = acc1[r];
    }
  }
  __syncthreads();
  if (tid < 10) {
    float tot = 0.f, mb_[18];
#pragma unroll
    for (int b = 0; b < 18; ++b) {
      float s = Cp[0][tid][b] + Cp[1][tid][b] + Cp[2][tid][b] + Cp[3][tid][b];
      float c = Cp[0][10][b] + Cp[1][10][b] + Cp[2][10][b] + Cp[3][10][b];
      float mb = s / fmaxf(c, 1.0f);
      mb_[b] = mb; tot += mb;
    }
    tot = fmaxf(tot, 1e-12f);
    float s = 0.f;
#pragma unroll
    for (int b = 0; b < 18; ++b) {
      float pb = mb_[b] / tot;
      s += pb * logf(fmaxf(pb, 1e-12f));
    }
    const float LOGN = 2.8903717578961645f; // log(18)
    // s'-mean folded in: out index (bc, p'=jp>>2, a'=tid)
    atomicAdd(&out[bc * 100 + (jp >> 2) * 10 + tid],
              0.25f * (LOGN + s) / LOGN);
  }
}

extern "C" void kernel_launch(void* const* d_in, const int* in_sizes, int n_in,
                              void* d_out, int out_size, void* d_ws, size_t ws_size,
                              hipStream_t stream) {
  (void)in_sizes; (void)n_in; (void)out_size; (void)ws_size;
  const float* x = (const float*)d_in[0];     // (4,8,4,2048) fp32
  const float* ker = (const float*)d_in[1];   // (20,769) fp32
  float* out = (float*)d_out;                 // 3200 fp32
  float* filt = (float*)d_ws;                 // 128*20*2048 fp32 (~21 MB)
  float2* tw = (float2*)(filt + (size_t)NS * NF * TT);  // 4096 float2 (32 KB)
  float2* Hc = tw + NFFT;                     // 20*4096 float2 (~655 KB)
  float2* Xs = Hc + (size_t)NF * NFFT;        // 128*4096 float2 (~4.2 MB)

  prep_kernel<<<16, 256, 0, stream>>>(tw, out);
  specf_kernel<<<NF + NS, 256, 0, stream>>>(x, ker, tw, Hc, Xs);
  convhil_kernel<<<NS * 10, 256, 0, stream>>>(Xs, Hc, tw, filt);
  mi_kernel<<<32 * 40, 256, 0, stream>>>(filt, out);
}

// Round 2
// 123.736 us; speedup vs baseline: 1.0334x; 1.0175x over previous
//
#include <hip/hip_runtime.h>
#include <math.h>

#define TT 2048
#define LK 769
#define NF 20
#define NS 128
#define NB 18
#define NFFT 4096

typedef __attribute__((ext_vector_type(8))) short short8;
typedef __attribute__((ext_vector_type(4))) float f32x4;

__device__ __forceinline__ float2 cmul(float2 a, float2 b) {
  return make_float2(a.x * b.x - a.y * b.y, a.x * b.y + a.y * b.x);
}
__device__ __forceinline__ float2 cmulc(float2 a, float2 b) {  // a * conj(b)
  return make_float2(a.x * b.x + a.y * b.y, a.y * b.x - a.x * b.y);
}
#define CADD(a, b) make_float2((a).x + (b).x, (a).y + (b).y)
#define CSUB(a, b) make_float2((a).x - (b).x, (a).y - (b).y)

// ---------------------------------------------------------------------------
// Radix-8 DIF forward stage (generic j).
// ---------------------------------------------------------------------------
__device__ __forceinline__ void fwd_r8(float2* z, const float2* __restrict__ tw,
                                       int tt, int Q) {
  const float C = 0.70710678118654752f;
  const int j = tt & (Q - 1);
  const int base = ((tt & ~(Q - 1)) << 3) + j;
  const float2 x0 = z[base],         x1 = z[base + Q];
  const float2 x2 = z[base + 2 * Q], x3 = z[base + 3 * Q];
  const float2 x4 = z[base + 4 * Q], x5 = z[base + 5 * Q];
  const float2 x6 = z[base + 6 * Q], x7 = z[base + 7 * Q];
  const float2 W1 = tw[4 * Q + j], W2 = tw[2 * Q + j], W4 = tw[Q + j];
  const float2 W3 = cmul(W1, W2);
  const float2 W5 = cmul(W1, W4);
  const float2 W6 = cmul(W2, W4);
  const float2 W7 = cmul(W3, W4);
  const float2 s0 = CADD(x0, x4), s1 = CSUB(x0, x4);
  const float2 s2 = CADD(x2, x6), s3 = CSUB(x2, x6);
  const float2 E0 = CADD(s0, s2), E2 = CSUB(s0, s2);
  const float2 E1 = make_float2(s1.x + s3.y, s1.y - s3.x);
  const float2 E3 = make_float2(s1.x - s3.y, s1.y + s3.x);
  const float2 t0 = CADD(x1, x5), t1 = CSUB(x1, x5);
  const float2 t2 = CADD(x3, x7), t3 = CSUB(x3, x7);
  const float2 O0 = CADD(t0, t2), O2 = CSUB(t0, t2);
  const float2 O1 = make_float2(t1.x + t3.y, t1.y - t3.x);
  const float2 O3 = make_float2(t1.x - t3.y, t1.y + t3.x);
  const float2 wO1 = make_float2(C * (O1.x + O1.y), C * (O1.y - O1.x));
  const float2 w3O3 = make_float2(C * (O3.y - O3.x), -C * (O3.x + O3.y));
  const float2 mO2 = make_float2(O2.y, -O2.x);
  const float2 y0 = CADD(E0, O0), y4 = CSUB(E0, O0);
  const float2 y1 = CADD(E1, wO1), y5 = CSUB(E1, wO1);
  const float2 y2 = CADD(E2, mO2), y6 = CSUB(E2, mO2);
  const float2 y3 = CADD(E3, w3O3), y7 = CSUB(E3, w3O3);
  z[base]         = y0;
  z[base + Q]     = cmul(y1, W1);
  z[base + 2 * Q] = cmul(y2, W2);
  z[base + 3 * Q] = cmul(y3, W3);
  z[base + 4 * Q] = cmul(y4, W4);
  z[base + 5 * Q] = cmul(y5, W5);
  z[base + 6 * Q] = cmul(y6, W6);
  z[base + 7 * Q] = cmul(y7, W7);
}

// Forward radix-8 stage specialized for Q=1 (j=0 -> all twiddles = 1).
__device__ __forceinline__ void fwd_r8_j0(float2* z, int base) {
  const float C = 0.70710678118654752f;
  const float2 x0 = z[base],     x1 = z[base + 1];
  const float2 x2 = z[base + 2], x3 = z[base + 3];
  const float2 x4 = z[base + 4], x5 = z[base + 5];
  const float2 x6 = z[base + 6], x7 = z[base + 7];
  const float2 s0 = CADD(x0, x4), s1 = CSUB(x0, x4);
  const float2 s2 = CADD(x2, x6), s3 = CSUB(x2, x6);
  const float2 E0 = CADD(s0, s2), E2 = CSUB(s0, s2);
  const float2 E1 = make_float2(s1.x + s3.y, s1.y - s3.x);
  const float2 E3 = make_float2(s1.x - s3.y, s1.y + s3.x);
  const float2 t0 = CADD(x1, x5), t1 = CSUB(x1, x5);
  const float2 t2 = CADD(x3, x7), t3 = CSUB(x3, x7);
  const float2 O0 = CADD(t0, t2), O2 = CSUB(t0, t2);
  const float2 O1 = make_float2(t1.x + t3.y, t1.y - t3.x);
  const float2 O3 = make_float2(t1.x - t3.y, t1.y + t3.x);
  const float2 wO1 = make_float2(C * (O1.x + O1.y), C * (O1.y - O1.x));
  const float2 w3O3 = make_float2(C * (O3.y - O3.x), -C * (O3.x + O3.y));
  const float2 mO2 = make_float2(O2.y, -O2.x);
  z[base]     = CADD(E0, O0);
  z[base + 4] = CSUB(E0, O0);
  z[base + 1] = CADD(E1, wO1);
  z[base + 5] = CSUB(E1, wO1);
  z[base + 2] = CADD(E2, mO2);
  z[base + 6] = CSUB(E2, mO2);
  z[base + 3] = CADD(E3, w3O3);
  z[base + 7] = CSUB(E3, w3O3);
}

// Radix-8 inverse stage (generic j), mirror of fwd.
__device__ __forceinline__ void inv_r8(float2* z, const float2* __restrict__ tw,
                                       int tt, int Q) {
  const float C = 0.70710678118654752f;
  const int j = tt & (Q - 1);
  const int base = ((tt & ~(Q - 1)) << 3) + j;
  const float2 W1 = tw[4 * Q + j], W2 = tw[2 * Q + j], W4 = tw[Q + j];
  const float2 W3 = cmul(W1, W2);
  const float2 W5 = cmul(W1, W4);
  const float2 W6 = cmul(W2, W4);
  const float2 W7 = cmul(W3, W4);
  const float2 u0 = z[base];
  const float2 u1 = cmulc(z[base + Q], W1);
  const float2 u2 = cmulc(z[base + 2 * Q], W2);
  const float2 u3 = cmulc(z[base + 3 * Q], W3);
  const float2 u4 = cmulc(z[base + 4 * Q], W4);
  const float2 u5 = cmulc(z[base + 5 * Q], W5);
  const float2 u6 = cmulc(z[base + 6 * Q], W6);
  const float2 u7 = cmulc(z[base + 7 * Q], W7);
  const float2 s0 = CADD(u0, u4), s1 = CSUB(u0, u4);
  const float2 s2 = CADD(u2, u6), s3 = CSUB(u2, u6);
  const float2 E0 = CADD(s0, s2), E2 = CSUB(s0, s2);
  const float2 E1 = make_float2(s1.x - s3.y, s1.y + s3.x);
  const float2 E3 = make_float2(s1.x + s3.y, s1.y - s3.x);
  const float2 t0 = CADD(u1, u5), t1 = CSUB(u1, u5);
  const float2 t2 = CADD(u3, u7), t3 = CSUB(u3, u7);
  const float2 O0 = CADD(t0, t2), O2 = CSUB(t0, t2);
  const float2 O1 = make_float2(t1.x - t3.y, t1.y + t3.x);
  const float2 O3 = make_float2(t1.x + t3.y, t1.y - t3.x);
  const float2 nO1 = make_float2(C * (O1.x - O1.y), C * (O1.x + O1.y));
  const float2 n3O3 = make_float2(-C * (O3.x + O3.y), C * (O3.x - O3.y));
  const float2 iO2 = make_float2(-O2.y, O2.x);
  z[base]         = CADD(E0, O0);
  z[base + 4 * Q] = CSUB(E0, O0);
  z[base + Q]     = CADD(E1, nO1);
  z[base + 5 * Q] = CSUB(E1, nO1);
  z[base + 2 * Q] = CADD(E2, iO2);
  z[base + 6 * Q] = CSUB(E2, iO2);
  z[base + 3 * Q] = CADD(E3, n3O3);
  z[base + 7 * Q] = CSUB(E3, n3O3);
}

// Inverse radix-8 Q=1 stage with the spectral multiply fused into the loads.
// u[m] = X[b8+m] * (conj(H1)+i*conj(H2))[b8+m]; j=0 -> no twiddles.
__device__ __forceinline__ void inv8_j0_fused(float2* z,
                                              const float2* __restrict__ Xn,
                                              const float2* __restrict__ H1,
                                              const float2* __restrict__ H2,
                                              int b8) {
  const float4* X4 = (const float4*)(Xn + b8);
  const float4* A4 = (const float4*)(H1 + b8);
  const float4* B4 = (const float4*)(H2 + b8);
  float2 u[8];
#pragma unroll
  for (int q = 0; q < 4; ++q) {
    float4 xv = X4[q], av = A4[q], bv = B4[q];
    float2 Cc0 = make_float2(av.x - bv.y, av.y + bv.x);
    float2 Cc1 = make_float2(av.z - bv.w, av.w + bv.z);
    u[2 * q]     = cmul(make_float2(xv.x, xv.y), Cc0);
    u[2 * q + 1] = cmul(make_float2(xv.z, xv.w), Cc1);
  }
  const float C = 0.70710678118654752f;
  const float2 s0 = CADD(u[0], u[4]), s1 = CSUB(u[0], u[4]);
  const float2 s2 = CADD(u[2], u[6]), s3 = CSUB(u[2], u[6]);
  const float2 E0 = CADD(s0, s2), E2 = CSUB(s0, s2);
  const float2 E1 = make_float2(s1.x - s3.y, s1.y + s3.x);
  const float2 E3 = make_float2(s1.x + s3.y, s1.y - s3.x);
  const float2 t0 = CADD(u[1], u[5]), t1 = CSUB(u[1], u[5]);
  const float2 t2 = CADD(u[3], u[7]), t3 = CSUB(u[3], u[7]);
  const float2 O0 = CADD(t0, t2), O2 = CSUB(t0, t2);
  const float2 O1 = make_float2(t1.x - t3.y, t1.y + t3.x);
  const float2 O3 = make_float2(t1.x + t3.y, t1.y - t3.x);
  const float2 nO1 = make_float2(C * (O1.x - O1.y), C * (O1.x + O1.y));
  const float2 n3O3 = make_float2(-C * (O3.x + O3.y), C * (O3.x - O3.y));
  const float2 iO2 = make_float2(-O2.y, O2.x);
  z[b8]     = CADD(E0, O0);
  z[b8 + 4] = CSUB(E0, O0);
  z[b8 + 1] = CADD(E1, nO1);
  z[b8 + 5] = CSUB(E1, nO1);
  z[b8 + 2] = CADD(E2, iO2);
  z[b8 + 6] = CSUB(E2, iO2);
  z[b8 + 3] = CADD(E3, n3O3);
  z[b8 + 7] = CSUB(E3, n3O3);
}

// ---------------------------------------------------------------------------
// Kernel P: twiddles (max index used = 2048+511) + zero out.
// ---------------------------------------------------------------------------
__global__ __launch_bounds__(256) void prep_kernel(float2* __restrict__ tw,
                                                   float* __restrict__ out) {
  const int i = blockIdx.x * 256 + threadIdx.x;   // grid 16 -> [0,4096)
  if (i == 0) {
    tw[0] = make_float2(1.f, 0.f);
  } else {
    int half = 1 << (31 - __clz(i));
    int j = i - half;
    float ang = -3.14159265358979323846f * (float)j / (float)half;
    float s, c;
    sincosf(ang, &s, &c);
    tw[i] = make_float2(c, s);
  }
  if (i < 3200) out[i] = 0.f;
}

// ---------------------------------------------------------------------------
// Kernel S: forward FFT4096 producers (digit-reversed order, kept as-is).
// ---------------------------------------------------------------------------
__global__ __launch_bounds__(256) void specf_kernel(const float* __restrict__ x,
                                                    const float* __restrict__ ker,
                                                    const float2* __restrict__ tw,
                                                    float2* __restrict__ Hc,
                                                    float2* __restrict__ Xs) {
  __shared__ __align__(16) float2 z[NFFT];
  const int tid = threadIdx.x;
  const int blk = blockIdx.x;
  if (blk < NF) {
    const float* kr = ker + blk * LK;
#pragma unroll
    for (int h = 0; h < 16; ++h) {
      int i = tid + 256 * h;
      float v = 0.f;
      if (i < LK) v = 0.5f * (kr[i] + kr[LK - 1 - i]);   // symmetrize
      z[i] = make_float2(v, 0.f);
    }
  } else {
    const float* xr = x + (size_t)(blk - NF) * TT;
#pragma unroll
    for (int h = 0; h < 16; ++h) {
      int i = tid + 256 * h;
      float v = 0.f;
      if (i < 2816) {                 // window index i -> original i-384
        int m = i - 384;
        if (m < 0) m = -m;            // reflect (edge excluded)
        if (m > 2047) m = 4094 - m;
        v = xr[m];
      }
      z[i] = make_float2(v, 0.f);
    }
  }
  __syncthreads();
  // forward: Q = 512 (cross-wave), 64, 8, 1
  fwd_r8(z, tw, tid, 512);
  fwd_r8(z, tw, tid + 256, 512);
  __syncthreads();
  fwd_r8(z, tw, tid, 64);
  fwd_r8(z, tw, tid + 256, 64);
  __builtin_amdgcn_wave_barrier();
  fwd_r8(z, tw, tid, 8);
  fwd_r8(z, tw, tid + 256, 8);
  __builtin_amdgcn_wave_barrier();
  fwd_r8_j0(z, tid << 3);
  fwd_r8_j0(z, (tid + 256) << 3);
  __syncthreads();
  if (blk < NF) {
    const float s = 1.0f / 4096.0f;   // fold IFFT4096 normalization into Hc
    float2* o = Hc + (size_t)blk * NFFT;
#pragma unroll
    for (int h = 0; h < 16; ++h) {
      int i = tid + 256 * h;
      float2 v = z[i];
      o[i] = make_float2(v.x * s, -v.y * s);   // conj
    }
  } else {
    float2* o = Xs + (size_t)(blk - NF) * NFFT;
#pragma unroll
    for (int h = 0; h < 16; ++h) {
      int i = tid + 256 * h;
      o[i] = z[i];
    }
  }
}

// ---------------------------------------------------------------------------
// Kernel A: frequency-domain conv + Hilbert.
// Spectral mult fused into the first inverse stage (j0). Epilogue writes amp
// floats + PACKED phase-bin bytes (bit-identical binning of the same atan2f
// value mi previously re-binned) -> pha plane never materialized.
// ---------------------------------------------------------------------------
__global__ __launch_bounds__(256) void convhil_kernel(const float2* __restrict__ Xs,
                                                      const float2* __restrict__ Hc,
                                                      const float2* __restrict__ tw,
                                                      float* __restrict__ filt,
                                                      unsigned int* __restrict__ binp) {
  __shared__ __align__(16) float2 z[NFFT];   // 32 KB
  const int tid = threadIdx.x;
  const int wv = tid >> 6;
  const int lane = tid & 63;
  const int ord = blockIdx.x;
  const int p = ord / NS;
  const int n = ord % NS;
  const int o1 = p;                          // pha band
  const int o2 = 10 + (9 - p);               // amp band (short with long)
  const float2* Xn = Xs + (size_t)n * NFFT;
  const float2* H1 = Hc + (size_t)o1 * NFFT;
  const float2* H2 = Hc + (size_t)o2 * NFFT;
  // ---- fused spectral-mult + inverse Q=1 stage (own-data only, no barrier) --
  inv8_j0_fused(z, Xn, H1, H2, tid << 3);
  inv8_j0_fused(z, Xn, H1, H2, (tid + 256) << 3);
  __builtin_amdgcn_wave_barrier();
  inv_r8(z, tw, tid, 8);
  inv_r8(z, tw, tid + 256, 8);
  __builtin_amdgcn_wave_barrier();
  inv_r8(z, tw, tid, 64);
  inv_r8(z, tw, tid + 256, 64);
  __syncthreads();
  inv_r8(z, tw, tid, 512);
  inv_r8(z, tw, tid + 256, 512);
  __syncthreads();
  // ---- grab y1,y2 into registers ----
  const int bA = 4 * tid;
  const int bB = 1024 + 4 * tid;
  float acc1A[4], acc1B[4], acc2A[4], acc2B[4];
#pragma unroll
  for (int r = 0; r < 4; ++r) {
    float2 vA = z[bA + r]; acc1A[r] = vA.x; acc2A[r] = vA.y;
    float2 vB = z[bB + r]; acc1B[r] = vB.x; acc2B[r] = vB.y;
  }
  __syncthreads();                                    // barrier 3
  // ---- forward radix-8 stage Q=256 (cross-wave) ----
  fwd_r8(z, tw, tid, 256);
  __syncthreads();                                    // barrier 4
  // ---- forward radix-8 stages Q=32, Q=4 (wave-local) ----
  fwd_r8(z, tw, tid, 32);
  __builtin_amdgcn_wave_barrier();
  fwd_r8(z, tw, tid, 4);
  __builtin_amdgcn_wave_barrier();
  // ---- forward radix-4 stage (Q=1), wave-local ----
#pragma unroll
  for (int h = 0; h < 2; ++h) {
    const int bf = 128 * wv + lane + 64 * h;
    const int base = bf << 2;
    const float2 x0 = z[base], x1 = z[base + 1];
    const float2 x2 = z[base + 2], x3 = z[base + 3];
    const float2 t0 = CADD(x0, x2), t1 = CSUB(x0, x2);
    const float2 t2 = CADD(x1, x3), t3 = CSUB(x1, x3);
    z[base]     = CADD(t0, t2);
    z[base + 1] = make_float2(t1.x + t3.y, t1.y - t3.x);
    z[base + 2] = CSUB(t0, t2);
    z[base + 3] = make_float2(t1.x - t3.y, t1.y + t3.x);
  }
  __builtin_amdgcn_wave_barrier();
  // ---- Hilbert mask, wave-local ----
#pragma unroll
  for (int i = 0; i < 8; ++i) {
    const int pp = 512 * wv + lane + 64 * i;
    if (pp != 0 && pp != 2) {
      if (pp & 2) { z[pp] = make_float2(0.f, 0.f); }
      else        { float2 v = z[pp]; z[pp] = make_float2(2.f * v.x, 2.f * v.y); }
    }
  }
  __builtin_amdgcn_wave_barrier();
  // ---- inverse radix-4 stage (Q=1), wave-local ----
#pragma unroll
  for (int h = 0; h < 2; ++h) {
    const int bf = 128 * wv + lane + 64 * h;
    const int base = bf << 2;
    const float2 u0 = z[base], u1 = z[base + 1];
    const float2 u2 = z[base + 2], u3 = z[base + 3];
    const float2 t0 = CADD(u0, u2), t1 = CSUB(u0, u2);
    const float2 t2 = CADD(u1, u3), t3 = CSUB(u1, u3);
    z[base]     = CADD(t0, t2);
    z[base + 1] = make_float2(t1.x - t3.y, t1.y + t3.x);
    z[base + 2] = CSUB(t0, t2);
    z[base + 3] = make_float2(t1.x + t3.y, t1.y - t3.x);
  }
  __builtin_amdgcn_wave_barrier();
  // ---- inverse radix-8 stages Q=4, Q=32 (wave-local) ----
  inv_r8(z, tw, tid, 4);
  __builtin_amdgcn_wave_barrier();
  inv_r8(z, tw, tid, 32);
  __builtin_amdgcn_wave_barrier();
  __syncthreads();                                    // barrier 5
  // ---- inverse radix-8 stage Q=256 (cross-wave) ----
  inv_r8(z, tw, tid, 256);
  __syncthreads();                                    // barrier 6
  // ---- epilogue: bins for o1, amp for o2 ----
  unsigned int* bp = binp + ((size_t)n * 10 + o1) * 512;
  float* out2 = filt + ((size_t)n * NF + o2) * TT;
  const float invN = 1.0f / 2048.0f;
  float amA[4], amB[4];
  unsigned int dA = 0, dB = 0;
#pragma unroll
  for (int r = 0; r < 4; ++r) {
    float2 wvA = z[bA + r];
    float h1 = wvA.y * invN - acc2A[r];
    float h2 = acc1A[r] - wvA.x * invN;
    float phA = atan2f(h1, acc1A[r]);
    amA[r] = sqrtf(fmaf(acc2A[r], acc2A[r], h2 * h2));
    int b = (int)floorf((phA + 3.14159274f) / 6.2831855f * 18.0f);
    b = b < 0 ? 0 : (b > 17 ? 17 : b);
    dA |= ((unsigned int)b) << (8 * r);
    float2 wvB = z[bB + r];
    float g1 = wvB.y * invN - acc2B[r];
    float g2 = acc1B[r] - wvB.x * invN;
    float phB = atan2f(g1, acc1B[r]);
    amB[r] = sqrtf(fmaf(acc2B[r], acc2B[r], g2 * g2));
    int b2 = (int)floorf((phB + 3.14159274f) / 6.2831855f * 18.0f);
    b2 = b2 < 0 ? 0 : (b2 > 17 ? 17 : b2);
    dB |= ((unsigned int)b2) << (8 * r);
  }
  bp[tid] = dA;          // bins for t in [4*tid, 4*tid+4)
  bp[tid + 256] = dB;    // bins for t in [1024+4*tid, ...)
  *(float4*)&out2[bA] = make_float4(amA[0], amA[1], amA[2], amA[3]);
  *(float4*)&out2[bB] = make_float4(amB[0], amB[1], amB[2], amB[3]);
}

// ---------------------------------------------------------------------------
// Kernel C: binned MI via MFMA. R2: (i) dead amp loads predicated off
// (n16>=10 lanes never use them), (ii) jp and jp+20 merged per block -- same
// jp&3 => identical ja => identical amp rows; A-fragments built once feed
// both planes' MFMAs, (iii) XCD-chunked swizzle keeps same-bc blocks on one
// XCD so repeat amp reads hit that XCD's L2. Arithmetic per jp unchanged.
// ---------------------------------------------------------------------------
__global__ __launch_bounds__(256) void mi_kernel(const float* __restrict__ filt,
                                                 const unsigned int* __restrict__ binp,
                                                 float* __restrict__ out) {
  __shared__ __align__(16) unsigned int idxA[512], idxB[512];
  __shared__ float Cp[2][4][12][19];
  const int tid = threadIdx.x;
  const int wave = tid >> 6;
  const int lane = tid & 63;
  // 640 blocks; swizzle so blocks of one bc (20 consecutive) share an XCD.
  const int bid = blockIdx.x;
  const int blk = (bid & 7) * 80 + (bid >> 3);
  const int bc = blk / 20, r = blk % 20;
  const int jpA = r, jpB = r + 20;           // same (jp & 3) => same ja
  const unsigned int* bpA =
      binp + ((size_t)(bc * 4 + jpA / 10) * 10 + (jpA % 10)) * 512;
  const unsigned int* bpB =
      binp + ((size_t)(bc * 4 + jpB / 10) * 10 + (jpB % 10)) * 512;
  idxA[tid] = bpA[tid];
  idxA[tid + 256] = bpA[tid + 256];
  idxB[tid] = bpB[tid];
  idxB[tid + 256] = bpB[tid + 256];
  __syncthreads();
  const int n16 = lane & 15;    // A row m / B col n / C col
  const int quad = lane >> 4;   // k-quad (0..3)
  const int aband = n16 < 10 ? n16 : 9;
  const int ja = (jpA & 3) + 4 * aband;   // identical for jpB
  const float* aptr = filt + ((size_t)(bc * 4 + ja / 10) * NF + 10 + (ja % 10)) * TT
                      + quad * 8;
  const bool isAmp = (n16 < 10);
  const bool isOne = (n16 == 10);
  f32x4 accA0 = {0.f, 0.f, 0.f, 0.f}, accA1 = {0.f, 0.f, 0.f, 0.f};
  f32x4 accB0 = {0.f, 0.f, 0.f, 0.f}, accB1 = {0.f, 0.f, 0.f, 0.f};
  const int s0 = wave * 16, s1 = s0 + 16;
  float4 p0 = make_float4(0.f, 0.f, 0.f, 0.f), p1 = p0;
  if (isAmp) {
    p0 = *(const float4*)(aptr + s0 * 32);
    p1 = *(const float4*)(aptr + s0 * 32 + 4);
  }
  for (int s = s0; s < s1; ++s) {
    float4 c0 = p0, c1 = p1;
    if (isAmp && s < s1 - 1) {
      p0 = *(const float4*)(aptr + (s + 1) * 32);
      p1 = *(const float4*)(aptr + (s + 1) * 32 + 4);
    }
    float a[8] = {c0.x, c0.y, c0.z, c0.w, c1.x, c1.y, c1.z, c1.w};
    short8 ah, am_, al;
#pragma unroll
    for (int j = 0; j < 8; ++j) {
      float v = isAmp ? a[j] : (isOne ? 1.0f : 0.0f);
      unsigned int u = __float_as_uint(v);
      float h = __uint_as_float(u & 0xFFFF0000u);
      float r1 = v - h;                       // exact (<=16 sig bits)
      unsigned int u2 = __float_as_uint(r1);
      float md = __uint_as_float(u2 & 0xFFFF0000u);
      float r2 = r1 - md;                     // exact (<=8 sig bits)
      unsigned int u3 = __float_as_uint(r2);
      ah[j] = (short)(u >> 16);
      am_[j] = (short)(u2 >> 16);
      al[j] = (short)(u3 >> 16);
    }
    const int dw = s * 8 + quad * 2;
    unsigned int dA0 = idxA[dw], dA1 = idxA[dw + 1];
    unsigned int dB0 = idxB[dw], dB1 = idxB[dw + 1];
    short8 bA0, bA1, bB0, bB1;
#pragma unroll
    for (int j = 0; j < 8; ++j) {
      unsigned int byA = ((j < 4 ? dA0 : dA1) >> ((j & 3) * 8)) & 0xFFu;
      unsigned int byB = ((j < 4 ? dB0 : dB1) >> ((j & 3) * 8)) & 0xFFu;
      bA0[j] = (byA == (unsigned int)n16) ? (short)0x3F80 : (short)0;
      bA1[j] = (byA == (unsigned int)(n16 + 16)) ? (short)0x3F80 : (short)0;
      bB0[j] = (byB == (unsigned int)n16) ? (short)0x3F80 : (short)0;
      bB1[j] = (byB == (unsigned int)(n16 + 16)) ? (short)0x3F80 : (short)0;
    }
    accA0 = __builtin_amdgcn_mfma_f32_16x16x32_bf16(ah, bA0, accA0, 0, 0, 0);
    accA0 = __builtin_amdgcn_mfma_f32_16x16x32_bf16(am_, bA0, accA0, 0, 0, 0);
    accA0 = __builtin_amdgcn_mfma_f32_16x16x32_bf16(al, bA0, accA0, 0, 0, 0);
    accA1 = __builtin_amdgcn_mfma_f32_16x16x32_bf16(ah, bA1, accA1, 0, 0, 0);
    accA1 = __builtin_amdgcn_mfma_f32_16x16x32_bf16(am_, bA1, accA1, 0, 0, 0);
    accA1 = __builtin_amdgcn_mfma_f32_16x16x32_bf16(al, bA1, accA1, 0, 0, 0);
    accB0 = __builtin_amdgcn_mfma_f32_16x16x32_bf16(ah, bB0, accB0, 0, 0, 0);
    accB0 = __builtin_amdgcn_mfma_f32_16x16x32_bf16(am_, bB0, accB0, 0, 0, 0);
    accB0 = __builtin_amdgcn_mfma_f32_16x16x32_bf16(al, bB0, accB0, 0, 0, 0);
    accB1 = __builtin_amdgcn_mfma_f32_16x16x32_bf16(ah, bB1, accB1, 0, 0, 0);
    accB1 = __builtin_amdgcn_mfma_f32_16x16x32_bf16(am_, bB1, accB1, 0, 0, 0);
    accB1 = __builtin_amdgcn_mfma_f32_16x16x32_bf16(al, bB1, accB1, 0, 0, 0);
  }
#pragma unroll
  for (int rr = 0; rr < 4; ++rr) {
    int row = quad * 4 + rr;
    if (row < 11) {
      Cp[0][wave][row][n16] = accA0[rr];
      Cp[1][wave][row][n16] = accB0[rr];
      if (n16 < 2) {
        Cp[0][wave][row][16 + n16] = accA1[rr];
        Cp[1][wave][row][16 + n16] = accB1[rr];
      }
    }
  }
  __syncthreads();
  int pl = -1, a_ = 0, jp_ = 0;
  if (tid < 10) { pl = 0; a_ = tid; jp_ = jpA; }
  else if (tid >= 64 && tid < 74) { pl = 1; a_ = tid - 64; jp_ = jpB; }
  if (pl >= 0) {
    float tot = 0.f, mb_[18];
#pragma unroll
    for (int b = 0; b < 18; ++b) {
      float s = Cp[pl][0][a_][b] + Cp[pl][1][a_][b] + Cp[pl][2][a_][b] + Cp[pl][3][a_][b];
      float c = Cp[pl][0][10][b] + Cp[pl][1][10][b] + Cp[pl][2][10][b] + Cp[pl][3][10][b];
      float mb = s / fmaxf(c, 1.0f);
      mb_[b] = mb; tot += mb;
    }
    tot = fmaxf(tot, 1e-12f);
    float s = 0.f;
#pragma unroll
    for (int b = 0; b < 18; ++b) {
      float pb = mb_[b] / tot;
      s += pb * logf(fmaxf(pb, 1e-12f));
    }
    const float LOGN = 2.8903717578961645f; // log(18)
    atomicAdd(&out[bc * 100 + (jp_ >> 2) * 10 + a_],
              0.25f * (LOGN + s) / LOGN);
  }
}

extern "C" void kernel_launch(void* const* d_in, const int* in_sizes, int n_in,
                              void* d_out, int out_size, void* d_ws, size_t ws_size,
                              hipStream_t stream) {
  (void)in_sizes; (void)n_in; (void)out_size; (void)ws_size;
  const float* x = (const float*)d_in[0];     // (4,8,4,2048) fp32
  const float* ker = (const float*)d_in[1];   // (20,769) fp32
  float* out = (float*)d_out;                 // 3200 fp32
  float* filt = (float*)d_ws;                 // 128*20*2048 fp32 (~21 MB; amp rows only)
  float2* tw = (float2*)(filt + (size_t)NS * NF * TT);  // 4096 float2 (32 KB)
  float2* Hc = tw + NFFT;                     // 20*4096 float2 (~655 KB)
  float2* Xs = Hc + (size_t)NF * NFFT;        // 128*4096 float2 (~4.2 MB)
  unsigned int* binp = (unsigned int*)(Xs + (size_t)NS * NFFT);  // 128*10*512 dwords

  prep_kernel<<<16, 256, 0, stream>>>(tw, out);
  specf_kernel<<<NF + NS, 256, 0, stream>>>(x, ker, tw, Hc, Xs);
  convhil_kernel<<<NS * 10, 256, 0, stream>>>(Xs, Hc, tw, filt, binp);
  mi_kernel<<<640, 256, 0, stream>>>(filt, binp, out);
}

// Round 3
// 123.688 us; speedup vs baseline: 1.0338x; 1.0004x over previous
//
#include <hip/hip_runtime.h>
#include <math.h>

#define TT 2048
#define LK 769
#define NF 20
#define NS 128
#define NB 18
#define NFFT 4096

// tw3 group offsets (in 4-float2 groups) per Q level
#define TW3_Q4   0
#define TW3_Q8   4
#define TW3_Q32  12
#define TW3_Q64  44
#define TW3_Q256 108
#define TW3_Q512 364
#define TW3_TOT  876

typedef __attribute__((ext_vector_type(8))) short short8;
typedef __attribute__((ext_vector_type(4))) float f32x4;
typedef __attribute__((ext_vector_type(4))) unsigned short us4;

__device__ __forceinline__ float2 cmul(float2 a, float2 b) {
  return make_float2(a.x * b.x - a.y * b.y, a.x * b.y + a.y * b.x);
}
__device__ __forceinline__ float2 cmulc(float2 a, float2 b) {  // a * conj(b)
  return make_float2(a.x * b.x + a.y * b.y, a.y * b.x - a.x * b.y);
}
#define CADD(a, b) make_float2((a).x + (b).x, (a).y + (b).y)
#define CSUB(a, b) make_float2((a).x - (b).x, (a).y - (b).y)

// ---------------------------------------------------------------------------
// Radix-8 DIF forward stage (generic j). W3/5/6/7 from precomputed tw3 table
// (prep builds them with the bit-identical cmul expressions).
// ---------------------------------------------------------------------------
__device__ __forceinline__ void fwd_r8(float2* z, const float2* __restrict__ tw,
                                       const float2* __restrict__ tw3q,
                                       int tt, int Q) {
  const float C = 0.70710678118654752f;
  const int j = tt & (Q - 1);
  const int base = ((tt & ~(Q - 1)) << 3) + j;
  const float2 x0 = z[base],         x1 = z[base + Q];
  const float2 x2 = z[base + 2 * Q], x3 = z[base + 3 * Q];
  const float2 x4 = z[base + 4 * Q], x5 = z[base + 5 * Q];
  const float2 x6 = z[base + 6 * Q], x7 = z[base + 7 * Q];
  const float2 W1 = tw[4 * Q + j], W2 = tw[2 * Q + j], W4 = tw[Q + j];
  const float4 w35 = *(const float4*)(tw3q + 4 * j);
  const float4 w67 = *(const float4*)(tw3q + 4 * j + 2);
  const float2 W3 = make_float2(w35.x, w35.y);
  const float2 W5 = make_float2(w35.z, w35.w);
  const float2 W6 = make_float2(w67.x, w67.y);
  const float2 W7 = make_float2(w67.z, w67.w);
  const float2 s0 = CADD(x0, x4), s1 = CSUB(x0, x4);
  const float2 s2 = CADD(x2, x6), s3 = CSUB(x2, x6);
  const float2 E0 = CADD(s0, s2), E2 = CSUB(s0, s2);
  const float2 E1 = make_float2(s1.x + s3.y, s1.y - s3.x);
  const float2 E3 = make_float2(s1.x - s3.y, s1.y + s3.x);
  const float2 t0 = CADD(x1, x5), t1 = CSUB(x1, x5);
  const float2 t2 = CADD(x3, x7), t3 = CSUB(x3, x7);
  const float2 O0 = CADD(t0, t2), O2 = CSUB(t0, t2);
  const float2 O1 = make_float2(t1.x + t3.y, t1.y - t3.x);
  const float2 O3 = make_float2(t1.x - t3.y, t1.y + t3.x);
  const float2 wO1 = make_float2(C * (O1.x + O1.y), C * (O1.y - O1.x));
  const float2 w3O3 = make_float2(C * (O3.y - O3.x), -C * (O3.x + O3.y));
  const float2 mO2 = make_float2(O2.y, -O2.x);
  const float2 y0 = CADD(E0, O0), y4 = CSUB(E0, O0);
  const float2 y1 = CADD(E1, wO1), y5 = CSUB(E1, wO1);
  const float2 y2 = CADD(E2, mO2), y6 = CSUB(E2, mO2);
  const float2 y3 = CADD(E3, w3O3), y7 = CSUB(E3, w3O3);
  z[base]         = y0;
  z[base + Q]     = cmul(y1, W1);
  z[base + 2 * Q] = cmul(y2, W2);
  z[base + 3 * Q] = cmul(y3, W3);
  z[base + 4 * Q] = cmul(y4, W4);
  z[base + 5 * Q] = cmul(y5, W5);
  z[base + 6 * Q] = cmul(y6, W6);
  z[base + 7 * Q] = cmul(y7, W7);
}

// Forward radix-8 stage specialized for Q=1 (j=0 -> all twiddles = 1).
__device__ __forceinline__ void fwd_r8_j0(float2* z, int base) {
  const float C = 0.70710678118654752f;
  const float2 x0 = z[base],     x1 = z[base + 1];
  const float2 x2 = z[base + 2], x3 = z[base + 3];
  const float2 x4 = z[base + 4], x5 = z[base + 5];
  const float2 x6 = z[base + 6], x7 = z[base + 7];
  const float2 s0 = CADD(x0, x4), s1 = CSUB(x0, x4);
  const float2 s2 = CADD(x2, x6), s3 = CSUB(x2, x6);
  const float2 E0 = CADD(s0, s2), E2 = CSUB(s0, s2);
  const float2 E1 = make_float2(s1.x + s3.y, s1.y - s3.x);
  const float2 E3 = make_float2(s1.x - s3.y, s1.y + s3.x);
  const float2 t0 = CADD(x1, x5), t1 = CSUB(x1, x5);
  const float2 t2 = CADD(x3, x7), t3 = CSUB(x3, x7);
  const float2 O0 = CADD(t0, t2), O2 = CSUB(t0, t2);
  const float2 O1 = make_float2(t1.x + t3.y, t1.y - t3.x);
  const float2 O3 = make_float2(t1.x - t3.y, t1.y + t3.x);
  const float2 wO1 = make_float2(C * (O1.x + O1.y), C * (O1.y - O1.x));
  const float2 w3O3 = make_float2(C * (O3.y - O3.x), -C * (O3.x + O3.y));
  const float2 mO2 = make_float2(O2.y, -O2.x);
  z[base]     = CADD(E0, O0);
  z[base + 4] = CSUB(E0, O0);
  z[base + 1] = CADD(E1, wO1);
  z[base + 5] = CSUB(E1, wO1);
  z[base + 2] = CADD(E2, mO2);
  z[base + 6] = CSUB(E2, mO2);
  z[base + 3] = CADD(E3, w3O3);
  z[base + 7] = CSUB(E3, w3O3);
}

// Radix-8 inverse stage (generic j), mirror of fwd.
__device__ __forceinline__ void inv_r8(float2* z, const float2* __restrict__ tw,
                                       const float2* __restrict__ tw3q,
                                       int tt, int Q) {
  const float C = 0.70710678118654752f;
  const int j = tt & (Q - 1);
  const int base = ((tt & ~(Q - 1)) << 3) + j;
  const float2 W1 = tw[4 * Q + j], W2 = tw[2 * Q + j], W4 = tw[Q + j];
  const float4 w35 = *(const float4*)(tw3q + 4 * j);
  const float4 w67 = *(const float4*)(tw3q + 4 * j + 2);
  const float2 W3 = make_float2(w35.x, w35.y);
  const float2 W5 = make_float2(w35.z, w35.w);
  const float2 W6 = make_float2(w67.x, w67.y);
  const float2 W7 = make_float2(w67.z, w67.w);
  const float2 u0 = z[base];
  const float2 u1 = cmulc(z[base + Q], W1);
  const float2 u2 = cmulc(z[base + 2 * Q], W2);
  const float2 u3 = cmulc(z[base + 3 * Q], W3);
  const float2 u4 = cmulc(z[base + 4 * Q], W4);
  const float2 u5 = cmulc(z[base + 5 * Q], W5);
  const float2 u6 = cmulc(z[base + 6 * Q], W6);
  const float2 u7 = cmulc(z[base + 7 * Q], W7);
  const float2 s0 = CADD(u0, u4), s1 = CSUB(u0, u4);
  const float2 s2 = CADD(u2, u6), s3 = CSUB(u2, u6);
  const float2 E0 = CADD(s0, s2), E2 = CSUB(s0, s2);
  const float2 E1 = make_float2(s1.x - s3.y, s1.y + s3.x);
  const float2 E3 = make_float2(s1.x + s3.y, s1.y - s3.x);
  const float2 t0 = CADD(u1, u5), t1 = CSUB(u1, u5);
  const float2 t2 = CADD(u3, u7), t3 = CSUB(u3, u7);
  const float2 O0 = CADD(t0, t2), O2 = CSUB(t0, t2);
  const float2 O1 = make_float2(t1.x - t3.y, t1.y + t3.x);
  const float2 O3 = make_float2(t1.x + t3.y, t1.y - t3.x);
  const float2 nO1 = make_float2(C * (O1.x - O1.y), C * (O1.x + O1.y));
  const float2 n3O3 = make_float2(-C * (O3.x + O3.y), C * (O3.x - O3.y));
  const float2 iO2 = make_float2(-O2.y, O2.x);
  z[base]         = CADD(E0, O0);
  z[base + 4 * Q] = CSUB(E0, O0);
  z[base + Q]     = CADD(E1, nO1);
  z[base + 5 * Q] = CSUB(E1, nO1);
  z[base + 2 * Q] = CADD(E2, iO2);
  z[base + 6 * Q] = CSUB(E2, iO2);
  z[base + 3 * Q] = CADD(E3, n3O3);
  z[base + 7 * Q] = CSUB(E3, n3O3);
}

// Inverse radix-8 Q=1 stage with the spectral multiply fused into the loads.
__device__ __forceinline__ void inv8_j0_fused(float2* z,
                                              const float2* __restrict__ Xn,
                                              const float2* __restrict__ H1,
                                              const float2* __restrict__ H2,
                                              int b8) {
  const float4* X4 = (const float4*)(Xn + b8);
  const float4* A4 = (const float4*)(H1 + b8);
  const float4* B4 = (const float4*)(H2 + b8);
  float2 u[8];
#pragma unroll
  for (int q = 0; q < 4; ++q) {
    float4 xv = X4[q], av = A4[q], bv = B4[q];
    float2 Cc0 = make_float2(av.x - bv.y, av.y + bv.x);
    float2 Cc1 = make_float2(av.z - bv.w, av.w + bv.z);
    u[2 * q]     = cmul(make_float2(xv.x, xv.y), Cc0);
    u[2 * q + 1] = cmul(make_float2(xv.z, xv.w), Cc1);
  }
  const float C = 0.70710678118654752f;
  const float2 s0 = CADD(u[0], u[4]), s1 = CSUB(u[0], u[4]);
  const float2 s2 = CADD(u[2], u[6]), s3 = CSUB(u[2], u[6]);
  const float2 E0 = CADD(s0, s2), E2 = CSUB(s0, s2);
  const float2 E1 = make_float2(s1.x - s3.y, s1.y + s3.x);
  const float2 E3 = make_float2(s1.x + s3.y, s1.y - s3.x);
  const float2 t0 = CADD(u[1], u[5]), t1 = CSUB(u[1], u[5]);
  const float2 t2 = CADD(u[3], u[7]), t3 = CSUB(u[3], u[7]);
  const float2 O0 = CADD(t0, t2), O2 = CSUB(t0, t2);
  const float2 O1 = make_float2(t1.x - t3.y, t1.y + t3.x);
  const float2 O3 = make_float2(t1.x + t3.y, t1.y - t3.x);
  const float2 nO1 = make_float2(C * (O1.x - O1.y), C * (O1.x + O1.y));
  const float2 n3O3 = make_float2(-C * (O3.x + O3.y), C * (O3.x - O3.y));
  const float2 iO2 = make_float2(-O2.y, O2.x);
  z[b8]     = CADD(E0, O0);
  z[b8 + 4] = CSUB(E0, O0);
  z[b8 + 1] = CADD(E1, nO1);
  z[b8 + 5] = CSUB(E1, nO1);
  z[b8 + 2] = CADD(E2, iO2);
  z[b8 + 6] = CSUB(E2, iO2);
  z[b8 + 3] = CADD(E3, n3O3);
  z[b8 + 7] = CSUB(E3, n3O3);
}

// ---------------------------------------------------------------------------
// Kernel P: twiddles + tw3 (W3/W5/W6/W7 per (Q,j), bit-identical cmul chain)
// + zero out. Blocks 0..15: tw/out; blocks 16..19: tw3.
// ---------------------------------------------------------------------------
__global__ __launch_bounds__(256) void prep_kernel(float2* __restrict__ tw,
                                                   float2* __restrict__ tw3,
                                                   float* __restrict__ out) {
  const int blk = blockIdx.x;
  const int tid = threadIdx.x;
  if (blk < 16) {
    const int i = blk * 256 + tid;
    if (i == 0) {
      tw[0] = make_float2(1.f, 0.f);
    } else {
      int half = 1 << (31 - __clz(i));
      int j = i - half;
      float ang = -3.14159265358979323846f * (float)j / (float)half;
      float s, c;
      sincosf(ang, &s, &c);
      tw[i] = make_float2(c, s);
    }
    if (i < 3200) out[i] = 0.f;
    return;
  }
  const int u = (blk - 16) * 256 + tid;
  if (u >= TW3_TOT) return;
  int Q, j;
  if (u < TW3_Q8)        { Q = 4;   j = u; }
  else if (u < TW3_Q32)  { Q = 8;   j = u - TW3_Q8; }
  else if (u < TW3_Q64)  { Q = 32;  j = u - TW3_Q32; }
  else if (u < TW3_Q256) { Q = 64;  j = u - TW3_Q64; }
  else if (u < TW3_Q512) { Q = 256; j = u - TW3_Q256; }
  else                   { Q = 512; j = u - TW3_Q512; }
  const float PI = 3.14159265358979323846f;
  // identical expressions to the tw fill (half = 4Q / 2Q / Q)
  float s, c;
  float2 W1, W2, W4;
  if (j == 0) { W1 = W2 = W4 = make_float2(1.f, 0.f); }
  else {
    float jf = (float)j;
    sincosf(-PI * jf / (float)(4 * Q), &s, &c); W1 = make_float2(c, s);
    sincosf(-PI * jf / (float)(2 * Q), &s, &c); W2 = make_float2(c, s);
    sincosf(-PI * jf / (float)(Q),     &s, &c); W4 = make_float2(c, s);
  }
  float2 W3 = cmul(W1, W2);
  float2 W5 = cmul(W1, W4);
  float2 W6 = cmul(W2, W4);
  float2 W7 = cmul(W3, W4);
  float4* o = (float4*)(tw3 + 4 * (size_t)u);
  o[0] = make_float4(W3.x, W3.y, W5.x, W5.y);
  o[1] = make_float4(W6.x, W6.y, W7.x, W7.y);
}

// ---------------------------------------------------------------------------
// Kernel S: forward FFT4096 producers (digit-reversed order, kept as-is).
// ---------------------------------------------------------------------------
__global__ __launch_bounds__(256) void specf_kernel(const float* __restrict__ x,
                                                    const float* __restrict__ ker,
                                                    const float2* __restrict__ tw,
                                                    const float2* __restrict__ tw3,
                                                    float2* __restrict__ Hc,
                                                    float2* __restrict__ Xs) {
  __shared__ __align__(16) float2 z[NFFT];
  const int tid = threadIdx.x;
  const int blk = blockIdx.x;
  if (blk < NF) {
    const float* kr = ker + blk * LK;
#pragma unroll
    for (int h = 0; h < 16; ++h) {
      int i = tid + 256 * h;
      float v = 0.f;
      if (i < LK) v = 0.5f * (kr[i] + kr[LK - 1 - i]);   // symmetrize
      z[i] = make_float2(v, 0.f);
    }
  } else {
    const float* xr = x + (size_t)(blk - NF) * TT;
#pragma unroll
    for (int h = 0; h < 16; ++h) {
      int i = tid + 256 * h;
      float v = 0.f;
      if (i < 2816) {                 // window index i -> original i-384
        int m = i - 384;
        if (m < 0) m = -m;            // reflect (edge excluded)
        if (m > 2047) m = 4094 - m;
        v = xr[m];
      }
      z[i] = make_float2(v, 0.f);
    }
  }
  __syncthreads();
  fwd_r8(z, tw, tw3 + 4 * TW3_Q512, tid, 512);
  fwd_r8(z, tw, tw3 + 4 * TW3_Q512, tid + 256, 512);
  __syncthreads();
  fwd_r8(z, tw, tw3 + 4 * TW3_Q64, tid, 64);
  fwd_r8(z, tw, tw3 + 4 * TW3_Q64, tid + 256, 64);
  __builtin_amdgcn_wave_barrier();
  fwd_r8(z, tw, tw3 + 4 * TW3_Q8, tid, 8);
  fwd_r8(z, tw, tw3 + 4 * TW3_Q8, tid + 256, 8);
  __builtin_amdgcn_wave_barrier();
  fwd_r8_j0(z, tid << 3);
  fwd_r8_j0(z, (tid + 256) << 3);
  __syncthreads();
  if (blk < NF) {
    const float s = 1.0f / 4096.0f;   // fold IFFT4096 normalization into Hc
    float2* o = Hc + (size_t)blk * NFFT;
#pragma unroll
    for (int h = 0; h < 16; ++h) {
      int i = tid + 256 * h;
      float2 v = z[i];
      o[i] = make_float2(v.x * s, -v.y * s);   // conj
    }
  } else {
    float2* o = Xs + (size_t)(blk - NF) * NFFT;
#pragma unroll
    for (int h = 0; h < 16; ++h) {
      int i = tid + 256 * h;
      o[i] = z[i];
    }
  }
}

// ---------------------------------------------------------------------------
// Kernel A: frequency-domain conv + Hilbert. Epilogue writes PACKED phase-bin
// bytes + the amp values PRE-SPLIT into 3 bf16 planes (bit-identical split
// mi previously did per-block, 5x redundantly). fp32 amp never materialized.
// amps layout: per row rid = n*10 + a, per t-group g=t/8: [ah x8][am x8][al x8]
// (24 ushorts = 48 B, 16B-aligned sub-vectors).
// ---------------------------------------------------------------------------
__global__ __launch_bounds__(256) void convhil_kernel(const float2* __restrict__ Xs,
                                                      const float2* __restrict__ Hc,
                                                      const float2* __restrict__ tw,
                                                      const float2* __restrict__ tw3,
                                                      unsigned short* __restrict__ amps,
                                                      unsigned int* __restrict__ binp) {
  __shared__ __align__(16) float2 z[NFFT];   // 32 KB
  const int tid = threadIdx.x;
  const int wv = tid >> 6;
  const int lane = tid & 63;
  const int ord = blockIdx.x;
  const int p = ord / NS;
  const int n = ord % NS;
  const int o1 = p;                          // pha band
  const int o2 = 10 + (9 - p);               // amp band (short with long)
  const float2* Xn = Xs + (size_t)n * NFFT;
  const float2* H1 = Hc + (size_t)o1 * NFFT;
  const float2* H2 = Hc + (size_t)o2 * NFFT;
  // ---- fused spectral-mult + inverse Q=1 stage ----
  inv8_j0_fused(z, Xn, H1, H2, tid << 3);
  inv8_j0_fused(z, Xn, H1, H2, (tid + 256) << 3);
  __builtin_amdgcn_wave_barrier();
  inv_r8(z, tw, tw3 + 4 * TW3_Q8, tid, 8);
  inv_r8(z, tw, tw3 + 4 * TW3_Q8, tid + 256, 8);
  __builtin_amdgcn_wave_barrier();
  inv_r8(z, tw, tw3 + 4 * TW3_Q64, tid, 64);
  inv_r8(z, tw, tw3 + 4 * TW3_Q64, tid + 256, 64);
  __syncthreads();
  inv_r8(z, tw, tw3 + 4 * TW3_Q512, tid, 512);
  inv_r8(z, tw, tw3 + 4 * TW3_Q512, tid + 256, 512);
  __syncthreads();
  // ---- grab y1,y2 into registers ----
  const int bA = 4 * tid;
  const int bB = 1024 + 4 * tid;
  float acc1A[4], acc1B[4], acc2A[4], acc2B[4];
#pragma unroll
  for (int r = 0; r < 4; ++r) {
    float2 vA = z[bA + r]; acc1A[r] = vA.x; acc2A[r] = vA.y;
    float2 vB = z[bB + r]; acc1B[r] = vB.x; acc2B[r] = vB.y;
  }
  __syncthreads();                                    // barrier 3
  // ---- forward radix-8 stage Q=256 (cross-wave) ----
  fwd_r8(z, tw, tw3 + 4 * TW3_Q256, tid, 256);
  __syncthreads();                                    // barrier 4
  // ---- forward radix-8 stages Q=32, Q=4 (wave-local) ----
  fwd_r8(z, tw, tw3 + 4 * TW3_Q32, tid, 32);
  __builtin_amdgcn_wave_barrier();
  fwd_r8(z, tw, tw3 + 4 * TW3_Q4, tid, 4);
  __builtin_amdgcn_wave_barrier();
  // ---- forward radix-4 stage (Q=1), wave-local ----
#pragma unroll
  for (int h = 0; h < 2; ++h) {
    const int bf = 128 * wv + lane + 64 * h;
    const int base = bf << 2;
    const float2 x0 = z[base], x1 = z[base + 1];
    const float2 x2 = z[base + 2], x3 = z[base + 3];
    const float2 t0 = CADD(x0, x2), t1 = CSUB(x0, x2);
    const float2 t2 = CADD(x1, x3), t3 = CSUB(x1, x3);
    z[base]     = CADD(t0, t2);
    z[base + 1] = make_float2(t1.x + t3.y, t1.y - t3.x);
    z[base + 2] = CSUB(t0, t2);
    z[base + 3] = make_float2(t1.x - t3.y, t1.y + t3.x);
  }
  __builtin_amdgcn_wave_barrier();
  // ---- Hilbert mask, wave-local ----
#pragma unroll
  for (int i = 0; i < 8; ++i) {
    const int pp = 512 * wv + lane + 64 * i;
    if (pp != 0 && pp != 2) {
      if (pp & 2) { z[pp] = make_float2(0.f, 0.f); }
      else        { float2 v = z[pp]; z[pp] = make_float2(2.f * v.x, 2.f * v.y); }
    }
  }
  __builtin_amdgcn_wave_barrier();
  // ---- inverse radix-4 stage (Q=1), wave-local ----
#pragma unroll
  for (int h = 0; h < 2; ++h) {
    const int bf = 128 * wv + lane + 64 * h;
    const int base = bf << 2;
    const float2 u0 = z[base], u1 = z[base + 1];
    const float2 u2 = z[base + 2], u3 = z[base + 3];
    const float2 t0 = CADD(u0, u2), t1 = CSUB(u0, u2);
    const float2 t2 = CADD(u1, u3), t3 = CSUB(u1, u3);
    z[base]     = CADD(t0, t2);
    z[base + 1] = make_float2(t1.x - t3.y, t1.y + t3.x);
    z[base + 2] = CSUB(t0, t2);
    z[base + 3] = make_float2(t1.x + t3.y, t1.y - t3.x);
  }
  __builtin_amdgcn_wave_barrier();
  // ---- inverse radix-8 stages Q=4, Q=32 (wave-local) ----
  inv_r8(z, tw, tw3 + 4 * TW3_Q4, tid, 4);
  __builtin_amdgcn_wave_barrier();
  inv_r8(z, tw, tw3 + 4 * TW3_Q32, tid, 32);
  __builtin_amdgcn_wave_barrier();
  __syncthreads();                                    // barrier 5
  // ---- inverse radix-8 stage Q=256 (cross-wave) ----
  inv_r8(z, tw, tw3 + 4 * TW3_Q256, tid, 256);
  __syncthreads();                                    // barrier 6
  // ---- epilogue: bins for o1, pre-split amp for o2 ----
  unsigned int* bp = binp + ((size_t)n * 10 + o1) * 512;
  const int rid = n * 10 + (o2 - 10);
  unsigned short* ap = amps + (size_t)rid * (TT * 3);
  const int offA = (tid >> 1) * 24 + (tid & 1) * 4;          // t-group tid/2
  const int offB = (128 + (tid >> 1)) * 24 + (tid & 1) * 4;  // t-group 128+tid/2
  const float invN = 1.0f / 2048.0f;
  us4 hA, mA, lA, hB, mB, lB;
  unsigned int dA = 0, dB = 0;
#pragma unroll
  for (int r = 0; r < 4; ++r) {
    float2 wvA = z[bA + r];
    float h1 = wvA.y * invN - acc2A[r];
    float h2 = acc1A[r] - wvA.x * invN;
    float phA = atan2f(h1, acc1A[r]);
    float vA = sqrtf(fmaf(acc2A[r], acc2A[r], h2 * h2));
    int b = (int)floorf((phA + 3.14159274f) / 6.2831855f * 18.0f);
    b = b < 0 ? 0 : (b > 17 ? 17 : b);
    dA |= ((unsigned int)b) << (8 * r);
    float2 wvB = z[bB + r];
    float g1 = wvB.y * invN - acc2B[r];
    float g2 = acc1B[r] - wvB.x * invN;
    float phB = atan2f(g1, acc1B[r]);
    float vB = sqrtf(fmaf(acc2B[r], acc2B[r], g2 * g2));
    int b2 = (int)floorf((phB + 3.14159274f) / 6.2831855f * 18.0f);
    b2 = b2 < 0 ? 0 : (b2 > 17 ? 17 : b2);
    dB |= ((unsigned int)b2) << (8 * r);
    // ---- 3-way exact bf16 split (bit-identical to old mi code) ----
    {
      unsigned int u = __float_as_uint(vA);
      float hf = __uint_as_float(u & 0xFFFF0000u);
      float r1 = vA - hf;
      unsigned int u2 = __float_as_uint(r1);
      float md = __uint_as_float(u2 & 0xFFFF0000u);
      float r2 = r1 - md;
      unsigned int u3 = __float_as_uint(r2);
      hA[r] = (unsigned short)(u >> 16);
      mA[r] = (unsigned short)(u2 >> 16);
      lA[r] = (unsigned short)(u3 >> 16);
    }
    {
      unsigned int u = __float_as_uint(vB);
      float hf = __uint_as_float(u & 0xFFFF0000u);
      float r1 = vB - hf;
      unsigned int u2 = __float_as_uint(r1);
      float md = __uint_as_float(u2 & 0xFFFF0000u);
      float r2 = r1 - md;
      unsigned int u3 = __float_as_uint(r2);
      hB[r] = (unsigned short)(u >> 16);
      mB[r] = (unsigned short)(u2 >> 16);
      lB[r] = (unsigned short)(u3 >> 16);
    }
  }
  bp[tid] = dA;
  bp[tid + 256] = dB;
  *(us4*)(ap + offA)      = hA;
  *(us4*)(ap + offA + 8)  = mA;
  *(us4*)(ap + offA + 16) = lA;
  *(us4*)(ap + offB)      = hB;
  *(us4*)(ap + offB + 8)  = mB;
  *(us4*)(ap + offB + 16) = lB;
}

// ---------------------------------------------------------------------------
// Kernel C: binned MI via MFMA. R3: A-fragments are direct short8 loads of
// the pre-split amp (zero repack VALU); bins 16/17 of planes A and B merged
// into ONE MFMA group (cols 0,1 = plane A, cols 2,3 = plane B): 9 MFMA/s.
// ---------------------------------------------------------------------------
__global__ __launch_bounds__(256) void mi_kernel(const unsigned short* __restrict__ amps,
                                                 const unsigned int* __restrict__ binp,
                                                 float* __restrict__ out) {
  __shared__ __align__(16) unsigned int idxA[512], idxB[512];
  __shared__ float Cp[2][4][12][19];
  const int tid = threadIdx.x;
  const int wave = tid >> 6;
  const int lane = tid & 63;
  // 640 blocks; swizzle so blocks of one bc (20 consecutive) share an XCD.
  const int bid = blockIdx.x;
  const int blk = (bid & 7) * 80 + (bid >> 3);
  const int bc = blk / 20, r = blk % 20;
  const int jpA = r, jpB = r + 20;           // same (jp & 3) => same ja
  const unsigned int* bpA =
      binp + ((size_t)(bc * 4 + jpA / 10) * 10 + (jpA % 10)) * 512;
  const unsigned int* bpB =
      binp + ((size_t)(bc * 4 + jpB / 10) * 10 + (jpB % 10)) * 512;
  idxA[tid] = bpA[tid];
  idxA[tid + 256] = bpA[tid + 256];
  idxB[tid] = bpB[tid];
  idxB[tid + 256] = bpB[tid + 256];
  __syncthreads();
  const int n16 = lane & 15;    // A row m / B col n / C col
  const int quad = lane >> 4;   // k-quad (0..3)
  const int aband = n16 < 10 ? n16 : 9;
  const int ja = (jpA & 3) + 4 * aband;   // identical for jpB
  const int nsig = bc * 4 + ja / 10;
  const int rid = nsig * 10 + (ja % 10);
  const unsigned short* aptr = amps + (size_t)rid * (TT * 3) + quad * 24;
  const bool isAmp = (n16 < 10);
  const bool isOne = (n16 == 10);
  // combined bins-16/17 target byte: cols 0,1 -> plane A; cols 2,3 -> plane B
  const int tgt1 = n16 < 2 ? n16 + 16 : (n16 < 4 ? n16 + 14 : 255);
  const bool useA1 = (n16 < 2);
  short8 aOne, aZero;
#pragma unroll
  for (int j = 0; j < 8; ++j) {
    aOne[j] = isOne ? (short)0x3F80 : (short)0;
    aZero[j] = 0;
  }
  f32x4 accA0 = {0.f, 0.f, 0.f, 0.f};
  f32x4 accB0 = {0.f, 0.f, 0.f, 0.f};
  f32x4 accC1 = {0.f, 0.f, 0.f, 0.f};
  const int s0 = wave * 16, s1 = s0 + 16;
  for (int s = s0; s < s1; ++s) {
    short8 ah, amv, alv;
    if (isAmp) {
      const unsigned short* g = aptr + s * 96;
      ah  = *(const short8*)(g);
      amv = *(const short8*)(g + 8);
      alv = *(const short8*)(g + 16);
    } else {
      ah = aOne; amv = aZero; alv = aZero;
    }
    const int dw = s * 8 + quad * 2;
    unsigned int dA0 = idxA[dw], dA1 = idxA[dw + 1];
    unsigned int dB0 = idxB[dw], dB1 = idxB[dw + 1];
    short8 bA0, bB0, bC1;
#pragma unroll
    for (int j = 0; j < 8; ++j) {
      unsigned int byA = ((j < 4 ? dA0 : dA1) >> ((j & 3) * 8)) & 0xFFu;
      unsigned int byB = ((j < 4 ? dB0 : dB1) >> ((j & 3) * 8)) & 0xFFu;
      bA0[j] = (byA == (unsigned int)n16) ? (short)0x3F80 : (short)0;
      bB0[j] = (byB == (unsigned int)n16) ? (short)0x3F80 : (short)0;
      unsigned int byC = useA1 ? byA : byB;
      bC1[j] = (byC == (unsigned int)tgt1) ? (short)0x3F80 : (short)0;
    }
    accA0 = __builtin_amdgcn_mfma_f32_16x16x32_bf16(ah,  bA0, accA0, 0, 0, 0);
    accA0 = __builtin_amdgcn_mfma_f32_16x16x32_bf16(amv, bA0, accA0, 0, 0, 0);
    accA0 = __builtin_amdgcn_mfma_f32_16x16x32_bf16(alv, bA0, accA0, 0, 0, 0);
    accB0 = __builtin_amdgcn_mfma_f32_16x16x32_bf16(ah,  bB0, accB0, 0, 0, 0);
    accB0 = __builtin_amdgcn_mfma_f32_16x16x32_bf16(amv, bB0, accB0, 0, 0, 0);
    accB0 = __builtin_amdgcn_mfma_f32_16x16x32_bf16(alv, bB0, accB0, 0, 0, 0);
    accC1 = __builtin_amdgcn_mfma_f32_16x16x32_bf16(ah,  bC1, accC1, 0, 0, 0);
    accC1 = __builtin_amdgcn_mfma_f32_16x16x32_bf16(amv, bC1, accC1, 0, 0, 0);
    accC1 = __builtin_amdgcn_mfma_f32_16x16x32_bf16(alv, bC1, accC1, 0, 0, 0);
  }
#pragma unroll
  for (int rr = 0; rr < 4; ++rr) {
    int row = quad * 4 + rr;
    if (row < 11) {
      Cp[0][wave][row][n16] = accA0[rr];
      Cp[1][wave][row][n16] = accB0[rr];
      if (n16 < 2)      Cp[0][wave][row][16 + n16] = accC1[rr];
      else if (n16 < 4) Cp[1][wave][row][14 + n16] = accC1[rr];
    }
  }
  __syncthreads();
  int pl = -1, a_ = 0, jp_ = 0;
  if (tid < 10) { pl = 0; a_ = tid; jp_ = jpA; }
  else if (tid >= 64 && tid < 74) { pl = 1; a_ = tid - 64; jp_ = jpB; }
  if (pl >= 0) {
    float tot = 0.f, mb_[18];
#pragma unroll
    for (int b = 0; b < 18; ++b) {
      float s = Cp[pl][0][a_][b] + Cp[pl][1][a_][b] + Cp[pl][2][a_][b] + Cp[pl][3][a_][b];
      float c = Cp[pl][0][10][b] + Cp[pl][1][10][b] + Cp[pl][2][10][b] + Cp[pl][3][10][b];
      float mb = s / fmaxf(c, 1.0f);
      mb_[b] = mb; tot += mb;
    }
    tot = fmaxf(tot, 1e-12f);
    float s = 0.f;
#pragma unroll
    for (int b = 0; b < 18; ++b) {
      float pb = mb_[b] / tot;
      s += pb * logf(fmaxf(pb, 1e-12f));
    }
    const float LOGN = 2.8903717578961645f; // log(18)
    atomicAdd(&out[bc * 100 + (jp_ >> 2) * 10 + a_],
              0.25f * (LOGN + s) / LOGN);
  }
}

extern "C" void kernel_launch(void* const* d_in, const int* in_sizes, int n_in,
                              void* d_out, int out_size, void* d_ws, size_t ws_size,
                              hipStream_t stream) {
  (void)in_sizes; (void)n_in; (void)out_size; (void)ws_size;
  const float* x = (const float*)d_in[0];     // (4,8,4,2048) fp32
  const float* ker = (const float*)d_in[1];   // (20,769) fp32
  float* out = (float*)d_out;                 // 3200 fp32
  unsigned short* amps = (unsigned short*)d_ws;          // 128*10*2048*3 ushorts (~15.7 MB)
  float2* tw  = (float2*)(amps + (size_t)NS * 10 * TT * 3);
  float2* tw3 = tw + NFFT;                    // 876*4 float2 (~28 KB)
  float2* Hc  = tw3 + 4 * TW3_TOT;            // 20*4096 float2 (~655 KB)
  float2* Xs  = Hc + (size_t)NF * NFFT;       // 128*4096 float2 (~4.2 MB)
  unsigned int* binp = (unsigned int*)(Xs + (size_t)NS * NFFT);  // 128*10*512 dwords

  prep_kernel<<<20, 256, 0, stream>>>(tw, tw3, out);
  specf_kernel<<<NF + NS, 256, 0, stream>>>(x, ker, tw, tw3, Hc, Xs);
  convhil_kernel<<<NS * 10, 256, 0, stream>>>(Xs, Hc, tw, tw3, amps, binp);
  mi_kernel<<<640, 256, 0, stream>>>(amps, binp, out);
}

// Round 4
// 122.257 us; speedup vs baseline: 1.0459x; 1.0117x over previous
//
#include <hip/hip_runtime.h>
#include <math.h>

#define TT 2048
#define LK 769
#define NF 20
#define NS 128
#define NB 18
#define NFFT 4096

// tw3 group offsets (in 4-float2 groups) per Q level
#define TW3_Q4   0
#define TW3_Q8   4
#define TW3_Q32  12
#define TW3_Q64  44
#define TW3_Q256 108
#define TW3_Q512 364
#define TW3_TOT  876

typedef __attribute__((ext_vector_type(8))) short short8;
typedef __attribute__((ext_vector_type(4))) float f32x4;
typedef __attribute__((ext_vector_type(4))) unsigned short us4;

__device__ __forceinline__ float2 cmul(float2 a, float2 b) {
  return make_float2(a.x * b.x - a.y * b.y, a.x * b.y + a.y * b.x);
}
__device__ __forceinline__ float2 cmulc(float2 a, float2 b) {  // a * conj(b)
  return make_float2(a.x * b.x + a.y * b.y, a.y * b.x - a.x * b.y);
}
#define CADD(a, b) make_float2((a).x + (b).x, (a).y + (b).y)
#define CSUB(a, b) make_float2((a).x - (b).x, (a).y - (b).y)

// ---------------------------------------------------------------------------
// Radix-8 DIF forward stage (generic j). W3/5/6/7 from precomputed tw3 table.
// ---------------------------------------------------------------------------
__device__ __forceinline__ void fwd_r8(float2* z, const float2* __restrict__ tw,
                                       const float2* __restrict__ tw3q,
                                       int tt, int Q) {
  const float C = 0.70710678118654752f;
  const int j = tt & (Q - 1);
  const int base = ((tt & ~(Q - 1)) << 3) + j;
  const float2 x0 = z[base],         x1 = z[base + Q];
  const float2 x2 = z[base + 2 * Q], x3 = z[base + 3 * Q];
  const float2 x4 = z[base + 4 * Q], x5 = z[base + 5 * Q];
  const float2 x6 = z[base + 6 * Q], x7 = z[base + 7 * Q];
  const float2 W1 = tw[4 * Q + j], W2 = tw[2 * Q + j], W4 = tw[Q + j];
  const float4 w35 = *(const float4*)(tw3q + 4 * j);
  const float4 w67 = *(const float4*)(tw3q + 4 * j + 2);
  const float2 W3 = make_float2(w35.x, w35.y);
  const float2 W5 = make_float2(w35.z, w35.w);
  const float2 W6 = make_float2(w67.x, w67.y);
  const float2 W7 = make_float2(w67.z, w67.w);
  const float2 s0 = CADD(x0, x4), s1 = CSUB(x0, x4);
  const float2 s2 = CADD(x2, x6), s3 = CSUB(x2, x6);
  const float2 E0 = CADD(s0, s2), E2 = CSUB(s0, s2);
  const float2 E1 = make_float2(s1.x + s3.y, s1.y - s3.x);
  const float2 E3 = make_float2(s1.x - s3.y, s1.y + s3.x);
  const float2 t0 = CADD(x1, x5), t1 = CSUB(x1, x5);
  const float2 t2 = CADD(x3, x7), t3 = CSUB(x3, x7);
  const float2 O0 = CADD(t0, t2), O2 = CSUB(t0, t2);
  const float2 O1 = make_float2(t1.x + t3.y, t1.y - t3.x);
  const float2 O3 = make_float2(t1.x - t3.y, t1.y + t3.x);
  const float2 wO1 = make_float2(C * (O1.x + O1.y), C * (O1.y - O1.x));
  const float2 w3O3 = make_float2(C * (O3.y - O3.x), -C * (O3.x + O3.y));
  const float2 mO2 = make_float2(O2.y, -O2.x);
  const float2 y0 = CADD(E0, O0), y4 = CSUB(E0, O0);
  const float2 y1 = CADD(E1, wO1), y5 = CSUB(E1, wO1);
  const float2 y2 = CADD(E2, mO2), y6 = CSUB(E2, mO2);
  const float2 y3 = CADD(E3, w3O3), y7 = CSUB(E3, w3O3);
  z[base]         = y0;
  z[base + Q]     = cmul(y1, W1);
  z[base + 2 * Q] = cmul(y2, W2);
  z[base + 3 * Q] = cmul(y3, W3);
  z[base + 4 * Q] = cmul(y4, W4);
  z[base + 5 * Q] = cmul(y5, W5);
  z[base + 6 * Q] = cmul(y6, W6);
  z[base + 7 * Q] = cmul(y7, W7);
}

// Forward radix-8 stage specialized for Q=1 (j=0 -> all twiddles = 1).
__device__ __forceinline__ void fwd_r8_j0(float2* z, int base) {
  const float C = 0.70710678118654752f;
  const float2 x0 = z[base],     x1 = z[base + 1];
  const float2 x2 = z[base + 2], x3 = z[base + 3];
  const float2 x4 = z[base + 4], x5 = z[base + 5];
  const float2 x6 = z[base + 6], x7 = z[base + 7];
  const float2 s0 = CADD(x0, x4), s1 = CSUB(x0, x4);
  const float2 s2 = CADD(x2, x6), s3 = CSUB(x2, x6);
  const float2 E0 = CADD(s0, s2), E2 = CSUB(s0, s2);
  const float2 E1 = make_float2(s1.x + s3.y, s1.y - s3.x);
  const float2 E3 = make_float2(s1.x - s3.y, s1.y + s3.x);
  const float2 t0 = CADD(x1, x5), t1 = CSUB(x1, x5);
  const float2 t2 = CADD(x3, x7), t3 = CSUB(x3, x7);
  const float2 O0 = CADD(t0, t2), O2 = CSUB(t0, t2);
  const float2 O1 = make_float2(t1.x + t3.y, t1.y - t3.x);
  const float2 O3 = make_float2(t1.x - t3.y, t1.y + t3.x);
  const float2 wO1 = make_float2(C * (O1.x + O1.y), C * (O1.y - O1.x));
  const float2 w3O3 = make_float2(C * (O3.y - O3.x), -C * (O3.x + O3.y));
  const float2 mO2 = make_float2(O2.y, -O2.x);
  z[base]     = CADD(E0, O0);
  z[base + 4] = CSUB(E0, O0);
  z[base + 1] = CADD(E1, wO1);
  z[base + 5] = CSUB(E1, wO1);
  z[base + 2] = CADD(E2, mO2);
  z[base + 6] = CSUB(E2, mO2);
  z[base + 3] = CADD(E3, w3O3);
  z[base + 7] = CSUB(E3, w3O3);
}

// Radix-8 inverse stage (generic j), mirror of fwd.
__device__ __forceinline__ void inv_r8(float2* z, const float2* __restrict__ tw,
                                       const float2* __restrict__ tw3q,
                                       int tt, int Q) {
  const float C = 0.70710678118654752f;
  const int j = tt & (Q - 1);
  const int base = ((tt & ~(Q - 1)) << 3) + j;
  const float2 W1 = tw[4 * Q + j], W2 = tw[2 * Q + j], W4 = tw[Q + j];
  const float4 w35 = *(const float4*)(tw3q + 4 * j);
  const float4 w67 = *(const float4*)(tw3q + 4 * j + 2);
  const float2 W3 = make_float2(w35.x, w35.y);
  const float2 W5 = make_float2(w35.z, w35.w);
  const float2 W6 = make_float2(w67.x, w67.y);
  const float2 W7 = make_float2(w67.z, w67.w);
  const float2 u0 = z[base];
  const float2 u1 = cmulc(z[base + Q], W1);
  const float2 u2 = cmulc(z[base + 2 * Q], W2);
  const float2 u3 = cmulc(z[base + 3 * Q], W3);
  const float2 u4 = cmulc(z[base + 4 * Q], W4);
  const float2 u5 = cmulc(z[base + 5 * Q], W5);
  const float2 u6 = cmulc(z[base + 6 * Q], W6);
  const float2 u7 = cmulc(z[base + 7 * Q], W7);
  const float2 s0 = CADD(u0, u4), s1 = CSUB(u0, u4);
  const float2 s2 = CADD(u2, u6), s3 = CSUB(u2, u6);
  const float2 E0 = CADD(s0, s2), E2 = CSUB(s0, s2);
  const float2 E1 = make_float2(s1.x - s3.y, s1.y + s3.x);
  const float2 E3 = make_float2(s1.x + s3.y, s1.y - s3.x);
  const float2 t0 = CADD(u1, u5), t1 = CSUB(u1, u5);
  const float2 t2 = CADD(u3, u7), t3 = CSUB(u3, u7);
  const float2 O0 = CADD(t0, t2), O2 = CSUB(t0, t2);
  const float2 O1 = make_float2(t1.x - t3.y, t1.y + t3.x);
  const float2 O3 = make_float2(t1.x + t3.y, t1.y - t3.x);
  const float2 nO1 = make_float2(C * (O1.x - O1.y), C * (O1.x + O1.y));
  const float2 n3O3 = make_float2(-C * (O3.x + O3.y), C * (O3.x - O3.y));
  const float2 iO2 = make_float2(-O2.y, O2.x);
  z[base]         = CADD(E0, O0);
  z[base + 4 * Q] = CSUB(E0, O0);
  z[base + Q]     = CADD(E1, nO1);
  z[base + 5 * Q] = CSUB(E1, nO1);
  z[base + 2 * Q] = CADD(E2, iO2);
  z[base + 6 * Q] = CSUB(E2, iO2);
  z[base + 3 * Q] = CADD(E3, n3O3);
  z[base + 7 * Q] = CSUB(E3, n3O3);
}

// Inverse radix-8 Q=512 stage, PRUNED: only outputs base+{0,Q,2Q,3Q} (< 2048)
// are ever consumed downstream (register grab + 2048-FFT touch z[0..2048)
// only), so the 4 CSUB outputs (indices >= 2048) are neither computed nor
// written. Inputs still read all 8 legs.
__device__ __forceinline__ void inv_r8_q512_top(float2* z,
                                                const float2* __restrict__ tw,
                                                const float2* __restrict__ tw3q,
                                                int tt) {
  const int Q = 512;
  const float C = 0.70710678118654752f;
  const int j = tt & (Q - 1);
  const int base = j;            // tt in [0,512)
  const float2 W1 = tw[4 * Q + j], W2 = tw[2 * Q + j], W4 = tw[Q + j];
  const float4 w35 = *(const float4*)(tw3q + 4 * j);
  const float4 w67 = *(const float4*)(tw3q + 4 * j + 2);
  const float2 W3 = make_float2(w35.x, w35.y);
  const float2 W5 = make_float2(w35.z, w35.w);
  const float2 W6 = make_float2(w67.x, w67.y);
  const float2 W7 = make_float2(w67.z, w67.w);
  const float2 u0 = z[base];
  const float2 u1 = cmulc(z[base + Q], W1);
  const float2 u2 = cmulc(z[base + 2 * Q], W2);
  const float2 u3 = cmulc(z[base + 3 * Q], W3);
  const float2 u4 = cmulc(z[base + 4 * Q], W4);
  const float2 u5 = cmulc(z[base + 5 * Q], W5);
  const float2 u6 = cmulc(z[base + 6 * Q], W6);
  const float2 u7 = cmulc(z[base + 7 * Q], W7);
  const float2 s0 = CADD(u0, u4), s1 = CSUB(u0, u4);
  const float2 s2 = CADD(u2, u6), s3 = CSUB(u2, u6);
  const float2 E0 = CADD(s0, s2), E2 = CSUB(s0, s2);
  const float2 E1 = make_float2(s1.x - s3.y, s1.y + s3.x);
  const float2 E3 = make_float2(s1.x + s3.y, s1.y - s3.x);
  const float2 t0 = CADD(u1, u5), t1 = CSUB(u1, u5);
  const float2 t2 = CADD(u3, u7), t3 = CSUB(u3, u7);
  const float2 O0 = CADD(t0, t2), O2 = CSUB(t0, t2);
  const float2 O1 = make_float2(t1.x - t3.y, t1.y + t3.x);
  const float2 O3 = make_float2(t1.x + t3.y, t1.y - t3.x);
  const float2 nO1 = make_float2(C * (O1.x - O1.y), C * (O1.x + O1.y));
  const float2 n3O3 = make_float2(-C * (O3.x + O3.y), C * (O3.x - O3.y));
  const float2 iO2 = make_float2(-O2.y, O2.x);
  z[base]         = CADD(E0, O0);
  z[base + Q]     = CADD(E1, nO1);
  z[base + 2 * Q] = CADD(E2, iO2);
  z[base + 3 * Q] = CADD(E3, n3O3);
}

// Inverse radix-8 Q=1 stage with the spectral multiply fused into the loads.
__device__ __forceinline__ void inv8_j0_fused(float2* z,
                                              const float2* __restrict__ Xn,
                                              const float2* __restrict__ H1,
                                              const float2* __restrict__ H2,
                                              int b8) {
  const float4* X4 = (const float4*)(Xn + b8);
  const float4* A4 = (const float4*)(H1 + b8);
  const float4* B4 = (const float4*)(H2 + b8);
  float2 u[8];
#pragma unroll
  for (int q = 0; q < 4; ++q) {
    float4 xv = X4[q], av = A4[q], bv = B4[q];
    float2 Cc0 = make_float2(av.x - bv.y, av.y + bv.x);
    float2 Cc1 = make_float2(av.z - bv.w, av.w + bv.z);
    u[2 * q]     = cmul(make_float2(xv.x, xv.y), Cc0);
    u[2 * q + 1] = cmul(make_float2(xv.z, xv.w), Cc1);
  }
  const float C = 0.70710678118654752f;
  const float2 s0 = CADD(u[0], u[4]), s1 = CSUB(u[0], u[4]);
  const float2 s2 = CADD(u[2], u[6]), s3 = CSUB(u[2], u[6]);
  const float2 E0 = CADD(s0, s2), E2 = CSUB(s0, s2);
  const float2 E1 = make_float2(s1.x - s3.y, s1.y + s3.x);
  const float2 E3 = make_float2(s1.x + s3.y, s1.y - s3.x);
  const float2 t0 = CADD(u[1], u[5]), t1 = CSUB(u[1], u[5]);
  const float2 t2 = CADD(u[3], u[7]), t3 = CSUB(u[3], u[7]);
  const float2 O0 = CADD(t0, t2), O2 = CSUB(t0, t2);
  const float2 O1 = make_float2(t1.x - t3.y, t1.y + t3.x);
  const float2 O3 = make_float2(t1.x + t3.y, t1.y - t3.x);
  const float2 nO1 = make_float2(C * (O1.x - O1.y), C * (O1.x + O1.y));
  const float2 n3O3 = make_float2(-C * (O3.x + O3.y), C * (O3.x - O3.y));
  const float2 iO2 = make_float2(-O2.y, O2.x);
  z[b8]     = CADD(E0, O0);
  z[b8 + 4] = CSUB(E0, O0);
  z[b8 + 1] = CADD(E1, nO1);
  z[b8 + 5] = CSUB(E1, nO1);
  z[b8 + 2] = CADD(E2, iO2);
  z[b8 + 6] = CSUB(E2, iO2);
  z[b8 + 3] = CADD(E3, n3O3);
  z[b8 + 7] = CSUB(E3, n3O3);
}

// ---------------------------------------------------------------------------
// Kernel P: twiddles + tw3 + zero out.
// ---------------------------------------------------------------------------
__global__ __launch_bounds__(256) void prep_kernel(float2* __restrict__ tw,
                                                   float2* __restrict__ tw3,
                                                   float* __restrict__ out) {
  const int blk = blockIdx.x;
  const int tid = threadIdx.x;
  if (blk < 16) {
    const int i = blk * 256 + tid;
    if (i == 0) {
      tw[0] = make_float2(1.f, 0.f);
    } else {
      int half = 1 << (31 - __clz(i));
      int j = i - half;
      float ang = -3.14159265358979323846f * (float)j / (float)half;
      float s, c;
      sincosf(ang, &s, &c);
      tw[i] = make_float2(c, s);
    }
    if (i < 3200) out[i] = 0.f;
    return;
  }
  const int u = (blk - 16) * 256 + tid;
  if (u >= TW3_TOT) return;
  int Q, j;
  if (u < TW3_Q8)        { Q = 4;   j = u; }
  else if (u < TW3_Q32)  { Q = 8;   j = u - TW3_Q8; }
  else if (u < TW3_Q64)  { Q = 32;  j = u - TW3_Q32; }
  else if (u < TW3_Q256) { Q = 64;  j = u - TW3_Q64; }
  else if (u < TW3_Q512) { Q = 256; j = u - TW3_Q256; }
  else                   { Q = 512; j = u - TW3_Q512; }
  const float PI = 3.14159265358979323846f;
  float s, c;
  float2 W1, W2, W4;
  if (j == 0) { W1 = W2 = W4 = make_float2(1.f, 0.f); }
  else {
    float jf = (float)j;
    sincosf(-PI * jf / (float)(4 * Q), &s, &c); W1 = make_float2(c, s);
    sincosf(-PI * jf / (float)(2 * Q), &s, &c); W2 = make_float2(c, s);
    sincosf(-PI * jf / (float)(Q),     &s, &c); W4 = make_float2(c, s);
  }
  float2 W3 = cmul(W1, W2);
  float2 W5 = cmul(W1, W4);
  float2 W6 = cmul(W2, W4);
  float2 W7 = cmul(W3, W4);
  float4* o = (float4*)(tw3 + 4 * (size_t)u);
  o[0] = make_float4(W3.x, W3.y, W5.x, W5.y);
  o[1] = make_float4(W6.x, W6.y, W7.x, W7.y);
}

// ---------------------------------------------------------------------------
// Kernel S: forward FFT4096 producers. R4: 512 threads/block (1 butterfly
// per thread per stage) -- 148 blocks run at ~1 block/CU, so the block's
// serial critical path IS the kernel duration; halving per-thread work
// halves it. Wave w still owns [512w, 512w+512) in the wave-local stages.
// ---------------------------------------------------------------------------
__global__ __launch_bounds__(512) void specf_kernel(const float* __restrict__ x,
                                                    const float* __restrict__ ker,
                                                    const float2* __restrict__ tw,
                                                    const float2* __restrict__ tw3,
                                                    float2* __restrict__ Hc,
                                                    float2* __restrict__ Xs) {
  __shared__ __align__(16) float2 z[NFFT];
  const int tid = threadIdx.x;
  const int blk = blockIdx.x;
  if (blk < NF) {
    const float* kr = ker + blk * LK;
#pragma unroll
    for (int h = 0; h < 8; ++h) {
      int i = tid + 512 * h;
      float v = 0.f;
      if (i < LK) v = 0.5f * (kr[i] + kr[LK - 1 - i]);   // symmetrize
      z[i] = make_float2(v, 0.f);
    }
  } else {
    const float* xr = x + (size_t)(blk - NF) * TT;
#pragma unroll
    for (int h = 0; h < 8; ++h) {
      int i = tid + 512 * h;
      float v = 0.f;
      if (i < 2816) {                 // window index i -> original i-384
        int m = i - 384;
        if (m < 0) m = -m;            // reflect (edge excluded)
        if (m > 2047) m = 4094 - m;
        v = xr[m];
      }
      z[i] = make_float2(v, 0.f);
    }
  }
  __syncthreads();
  fwd_r8(z, tw, tw3 + 4 * TW3_Q512, tid, 512);
  __syncthreads();
  fwd_r8(z, tw, tw3 + 4 * TW3_Q64, tid, 64);
  __builtin_amdgcn_wave_barrier();
  fwd_r8(z, tw, tw3 + 4 * TW3_Q8, tid, 8);
  __builtin_amdgcn_wave_barrier();
  fwd_r8_j0(z, tid << 3);
  __syncthreads();
  if (blk < NF) {
    const float s = 1.0f / 4096.0f;   // fold IFFT4096 normalization into Hc
    float2* o = Hc + (size_t)blk * NFFT;
#pragma unroll
    for (int h = 0; h < 8; ++h) {
      int i = tid + 512 * h;
      float2 v = z[i];
      o[i] = make_float2(v.x * s, -v.y * s);   // conj
    }
  } else {
    float2* o = Xs + (size_t)(blk - NF) * NFFT;
#pragma unroll
    for (int h = 0; h < 8; ++h) {
      int i = tid + 512 * h;
      o[i] = z[i];
    }
  }
}

// ---------------------------------------------------------------------------
// Kernel A: frequency-domain conv + Hilbert. R4: last inverse-4096 stage
// pruned to the [0,2048) outputs. Epilogue: packed bins + pre-split bf16 amp.
// ---------------------------------------------------------------------------
__global__ __launch_bounds__(256) void convhil_kernel(const float2* __restrict__ Xs,
                                                      const float2* __restrict__ Hc,
                                                      const float2* __restrict__ tw,
                                                      const float2* __restrict__ tw3,
                                                      unsigned short* __restrict__ amps,
                                                      unsigned int* __restrict__ binp) {
  __shared__ __align__(16) float2 z[NFFT];   // 32 KB
  const int tid = threadIdx.x;
  const int wv = tid >> 6;
  const int lane = tid & 63;
  const int ord = blockIdx.x;
  const int p = ord / NS;
  const int n = ord % NS;
  const int o1 = p;                          // pha band
  const int o2 = 10 + (9 - p);               // amp band (short with long)
  const float2* Xn = Xs + (size_t)n * NFFT;
  const float2* H1 = Hc + (size_t)o1 * NFFT;
  const float2* H2 = Hc + (size_t)o2 * NFFT;
  // ---- fused spectral-mult + inverse Q=1 stage ----
  inv8_j0_fused(z, Xn, H1, H2, tid << 3);
  inv8_j0_fused(z, Xn, H1, H2, (tid + 256) << 3);
  __builtin_amdgcn_wave_barrier();
  inv_r8(z, tw, tw3 + 4 * TW3_Q8, tid, 8);
  inv_r8(z, tw, tw3 + 4 * TW3_Q8, tid + 256, 8);
  __builtin_amdgcn_wave_barrier();
  inv_r8(z, tw, tw3 + 4 * TW3_Q64, tid, 64);
  inv_r8(z, tw, tw3 + 4 * TW3_Q64, tid + 256, 64);
  __syncthreads();
  inv_r8_q512_top(z, tw, tw3 + 4 * TW3_Q512, tid);
  inv_r8_q512_top(z, tw, tw3 + 4 * TW3_Q512, tid + 256);
  __syncthreads();
  // ---- grab y1,y2 into registers ----
  const int bA = 4 * tid;
  const int bB = 1024 + 4 * tid;
  float acc1A[4], acc1B[4], acc2A[4], acc2B[4];
#pragma unroll
  for (int r = 0; r < 4; ++r) {
    float2 vA = z[bA + r]; acc1A[r] = vA.x; acc2A[r] = vA.y;
    float2 vB = z[bB + r]; acc1B[r] = vB.x; acc2B[r] = vB.y;
  }
  __syncthreads();                                    // barrier 3
  // ---- forward radix-8 stage Q=256 (cross-wave) ----
  fwd_r8(z, tw, tw3 + 4 * TW3_Q256, tid, 256);
  __syncthreads();                                    // barrier 4
  // ---- forward radix-8 stages Q=32, Q=4 (wave-local) ----
  fwd_r8(z, tw, tw3 + 4 * TW3_Q32, tid, 32);
  __builtin_amdgcn_wave_barrier();
  fwd_r8(z, tw, tw3 + 4 * TW3_Q4, tid, 4);
  __builtin_amdgcn_wave_barrier();
  // ---- forward radix-4 stage (Q=1), wave-local ----
#pragma unroll
  for (int h = 0; h < 2; ++h) {
    const int bf = 128 * wv + lane + 64 * h;
    const int base = bf << 2;
    const float2 x0 = z[base], x1 = z[base + 1];
    const float2 x2 = z[base + 2], x3 = z[base + 3];
    const float2 t0 = CADD(x0, x2), t1 = CSUB(x0, x2);
    const float2 t2 = CADD(x1, x3), t3 = CSUB(x1, x3);
    z[base]     = CADD(t0, t2);
    z[base + 1] = make_float2(t1.x + t3.y, t1.y - t3.x);
    z[base + 2] = CSUB(t0, t2);
    z[base + 3] = make_float2(t1.x - t3.y, t1.y + t3.x);
  }
  __builtin_amdgcn_wave_barrier();
  // ---- Hilbert mask, wave-local ----
#pragma unroll
  for (int i = 0; i < 8; ++i) {
    const int pp = 512 * wv + lane + 64 * i;
    if (pp != 0 && pp != 2) {
      if (pp & 2) { z[pp] = make_float2(0.f, 0.f); }
      else        { float2 v = z[pp]; z[pp] = make_float2(2.f * v.x, 2.f * v.y); }
    }
  }
  __builtin_amdgcn_wave_barrier();
  // ---- inverse radix-4 stage (Q=1), wave-local ----
#pragma unroll
  for (int h = 0; h < 2; ++h) {
    const int bf = 128 * wv + lane + 64 * h;
    const int base = bf << 2;
    const float2 u0 = z[base], u1 = z[base + 1];
    const float2 u2 = z[base + 2], u3 = z[base + 3];
    const float2 t0 = CADD(u0, u2), t1 = CSUB(u0, u2);
    const float2 t2 = CADD(u1, u3), t3 = CSUB(u1, u3);
    z[base]     = CADD(t0, t2);
    z[base + 1] = make_float2(t1.x - t3.y, t1.y + t3.x);
    z[base + 2] = CSUB(t0, t2);
    z[base + 3] = make_float2(t1.x + t3.y, t1.y - t3.x);
  }
  __builtin_amdgcn_wave_barrier();
  // ---- inverse radix-8 stages Q=4, Q=32 (wave-local) ----
  inv_r8(z, tw, tw3 + 4 * TW3_Q4, tid, 4);
  __builtin_amdgcn_wave_barrier();
  inv_r8(z, tw, tw3 + 4 * TW3_Q32, tid, 32);
  __builtin_amdgcn_wave_barrier();
  __syncthreads();                                    // barrier 5
  // ---- inverse radix-8 stage Q=256 (cross-wave) ----
  inv_r8(z, tw, tw3 + 4 * TW3_Q256, tid, 256);
  __syncthreads();                                    // barrier 6
  // ---- epilogue: bins for o1, pre-split amp for o2 ----
  unsigned int* bp = binp + ((size_t)n * 10 + o1) * 512;
  const int rid = n * 10 + (o2 - 10);
  unsigned short* ap = amps + (size_t)rid * (TT * 3);
  const int offA = (tid >> 1) * 24 + (tid & 1) * 4;          // t-group tid/2
  const int offB = (128 + (tid >> 1)) * 24 + (tid & 1) * 4;  // t-group 128+tid/2
  const float invN = 1.0f / 2048.0f;
  us4 hA, mA, lA, hB, mB, lB;
  unsigned int dA = 0, dB = 0;
#pragma unroll
  for (int r = 0; r < 4; ++r) {
    float2 wvA = z[bA + r];
    float h1 = wvA.y * invN - acc2A[r];
    float h2 = acc1A[r] - wvA.x * invN;
    float phA = atan2f(h1, acc1A[r]);
    float vA = sqrtf(fmaf(acc2A[r], acc2A[r], h2 * h2));
    int b = (int)floorf((phA + 3.14159274f) / 6.2831855f * 18.0f);
    b = b < 0 ? 0 : (b > 17 ? 17 : b);
    dA |= ((unsigned int)b) << (8 * r);
    float2 wvB = z[bB + r];
    float g1 = wvB.y * invN - acc2B[r];
    float g2 = acc1B[r] - wvB.x * invN;
    float phB = atan2f(g1, acc1B[r]);
    float vB = sqrtf(fmaf(acc2B[r], acc2B[r], g2 * g2));
    int b2 = (int)floorf((phB + 3.14159274f) / 6.2831855f * 18.0f);
    b2 = b2 < 0 ? 0 : (b2 > 17 ? 17 : b2);
    dB |= ((unsigned int)b2) << (8 * r);
    // ---- 3-way exact bf16 split (bit-identical to original mi code) ----
    {
      unsigned int u = __float_as_uint(vA);
      float hf = __uint_as_float(u & 0xFFFF0000u);
      float r1 = vA - hf;
      unsigned int u2 = __float_as_uint(r1);
      float md = __uint_as_float(u2 & 0xFFFF0000u);
      float r2 = r1 - md;
      unsigned int u3 = __float_as_uint(r2);
      hA[r] = (unsigned short)(u >> 16);
      mA[r] = (unsigned short)(u2 >> 16);
      lA[r] = (unsigned short)(u3 >> 16);
    }
    {
      unsigned int u = __float_as_uint(vB);
      float hf = __uint_as_float(u & 0xFFFF0000u);
      float r1 = vB - hf;
      unsigned int u2 = __float_as_uint(r1);
      float md = __uint_as_float(u2 & 0xFFFF0000u);
      float r2 = r1 - md;
      unsigned int u3 = __float_as_uint(r2);
      hB[r] = (unsigned short)(u >> 16);
      mB[r] = (unsigned short)(u2 >> 16);
      lB[r] = (unsigned short)(u3 >> 16);
    }
  }
  bp[tid] = dA;
  bp[tid + 256] = dB;
  *(us4*)(ap + offA)      = hA;
  *(us4*)(ap + offA + 8)  = mA;
  *(us4*)(ap + offA + 16) = lA;
  *(us4*)(ap + offB)      = hB;
  *(us4*)(ap + offB + 8)  = mB;
  *(us4*)(ap + offB + 16) = lB;
}

// ---------------------------------------------------------------------------
// Kernel C: binned MI via MFMA (unchanged from R3).
// ---------------------------------------------------------------------------
__global__ __launch_bounds__(256) void mi_kernel(const unsigned short* __restrict__ amps,
                                                 const unsigned int* __restrict__ binp,
                                                 float* __restrict__ out) {
  __shared__ __align__(16) unsigned int idxA[512], idxB[512];
  __shared__ float Cp[2][4][12][19];
  const int tid = threadIdx.x;
  const int wave = tid >> 6;
  const int lane = tid & 63;
  const int bid = blockIdx.x;
  const int blk = (bid & 7) * 80 + (bid >> 3);
  const int bc = blk / 20, r = blk % 20;
  const int jpA = r, jpB = r + 20;           // same (jp & 3) => same ja
  const unsigned int* bpA =
      binp + ((size_t)(bc * 4 + jpA / 10) * 10 + (jpA % 10)) * 512;
  const unsigned int* bpB =
      binp + ((size_t)(bc * 4 + jpB / 10) * 10 + (jpB % 10)) * 512;
  idxA[tid] = bpA[tid];
  idxA[tid + 256] = bpA[tid + 256];
  idxB[tid] = bpB[tid];
  idxB[tid + 256] = bpB[tid + 256];
  __syncthreads();
  const int n16 = lane & 15;    // A row m / B col n / C col
  const int quad = lane >> 4;   // k-quad (0..3)
  const int aband = n16 < 10 ? n16 : 9;
  const int ja = (jpA & 3) + 4 * aband;   // identical for jpB
  const int nsig = bc * 4 + ja / 10;
  const int rid = nsig * 10 + (ja % 10);
  const unsigned short* aptr = amps + (size_t)rid * (TT * 3) + quad * 24;
  const bool isAmp = (n16 < 10);
  const bool isOne = (n16 == 10);
  const int tgt1 = n16 < 2 ? n16 + 16 : (n16 < 4 ? n16 + 14 : 255);
  const bool useA1 = (n16 < 2);
  short8 aOne, aZero;
#pragma unroll
  for (int j = 0; j < 8; ++j) {
    aOne[j] = isOne ? (short)0x3F80 : (short)0;
    aZero[j] = 0;
  }
  f32x4 accA0 = {0.f, 0.f, 0.f, 0.f};
  f32x4 accB0 = {0.f, 0.f, 0.f, 0.f};
  f32x4 accC1 = {0.f, 0.f, 0.f, 0.f};
  const int s0 = wave * 16, s1 = s0 + 16;
  for (int s = s0; s < s1; ++s) {
    short8 ah, amv, alv;
    if (isAmp) {
      const unsigned short* g = aptr + s * 96;
      ah  = *(const short8*)(g);
      amv = *(const short8*)(g + 8);
      alv = *(const short8*)(g + 16);
    } else {
      ah = aOne; amv = aZero; alv = aZero;
    }
    const int dw = s * 8 + quad * 2;
    unsigned int dA0 = idxA[dw], dA1 = idxA[dw + 1];
    unsigned int dB0 = idxB[dw], dB1 = idxB[dw + 1];
    short8 bA0, bB0, bC1;
#pragma unroll
    for (int j = 0; j < 8; ++j) {
      unsigned int byA = ((j < 4 ? dA0 : dA1) >> ((j & 3) * 8)) & 0xFFu;
      unsigned int byB = ((j < 4 ? dB0 : dB1) >> ((j & 3) * 8)) & 0xFFu;
      bA0[j] = (byA == (unsigned int)n16) ? (short)0x3F80 : (short)0;
      bB0[j] = (byB == (unsigned int)n16) ? (short)0x3F80 : (short)0;
      unsigned int byC = useA1 ? byA : byB;
      bC1[j] = (byC == (unsigned int)tgt1) ? (short)0x3F80 : (short)0;
    }
    accA0 = __builtin_amdgcn_mfma_f32_16x16x32_bf16(ah,  bA0, accA0, 0, 0, 0);
    accA0 = __builtin_amdgcn_mfma_f32_16x16x32_bf16(amv, bA0, accA0, 0, 0, 0);
    accA0 = __builtin_amdgcn_mfma_f32_16x16x32_bf16(alv, bA0, accA0, 0, 0, 0);
    accB0 = __builtin_amdgcn_mfma_f32_16x16x32_bf16(ah,  bB0, accB0, 0, 0, 0);
    accB0 = __builtin_amdgcn_mfma_f32_16x16x32_bf16(amv, bB0, accB0, 0, 0, 0);
    accB0 = __builtin_amdgcn_mfma_f32_16x16x32_bf16(alv, bB0, accB0, 0, 0, 0);
    accC1 = __builtin_amdgcn_mfma_f32_16x16x32_bf16(ah,  bC1, accC1, 0, 0, 0);
    accC1 = __builtin_amdgcn_mfma_f32_16x16x32_bf16(amv, bC1, accC1, 0, 0, 0);
    accC1 = __builtin_amdgcn_mfma_f32_16x16x32_bf16(alv, bC1, accC1, 0, 0, 0);
  }
#pragma unroll
  for (int rr = 0; rr < 4; ++rr) {
    int row = quad * 4 + rr;
    if (row < 11) {
      Cp[0][wave][row][n16] = accA0[rr];
      Cp[1][wave][row][n16] = accB0[rr];
      if (n16 < 2)      Cp[0][wave][row][16 + n16] = accC1[rr];
      else if (n16 < 4) Cp[1][wave][row][14 + n16] = accC1[rr];
    }
  }
  __syncthreads();
  int pl = -1, a_ = 0, jp_ = 0;
  if (tid < 10) { pl = 0; a_ = tid; jp_ = jpA; }
  else if (tid >= 64 && tid < 74) { pl = 1; a_ = tid - 64; jp_ = jpB; }
  if (pl >= 0) {
    float tot = 0.f, mb_[18];
#pragma unroll
    for (int b = 0; b < 18; ++b) {
      float s = Cp[pl][0][a_][b] + Cp[pl][1][a_][b] + Cp[pl][2][a_][b] + Cp[pl][3][a_][b];
      float c = Cp[pl][0][10][b] + Cp[pl][1][10][b] + Cp[pl][2][10][b] + Cp[pl][3][10][b];
      float mb = s / fmaxf(c, 1.0f);
      mb_[b] = mb; tot += mb;
    }
    tot = fmaxf(tot, 1e-12f);
    float s = 0.f;
#pragma unroll
    for (int b = 0; b < 18; ++b) {
      float pb = mb_[b] / tot;
      s += pb * logf(fmaxf(pb, 1e-12f));
    }
    const float LOGN = 2.8903717578961645f; // log(18)
    atomicAdd(&out[bc * 100 + (jp_ >> 2) * 10 + a_],
              0.25f * (LOGN + s) / LOGN);
  }
}

extern "C" void kernel_launch(void* const* d_in, const int* in_sizes, int n_in,
                              void* d_out, int out_size, void* d_ws, size_t ws_size,
                              hipStream_t stream) {
  (void)in_sizes; (void)n_in; (void)out_size; (void)ws_size;
  const float* x = (const float*)d_in[0];     // (4,8,4,2048) fp32
  const float* ker = (const float*)d_in[1];   // (20,769) fp32
  float* out = (float*)d_out;                 // 3200 fp32
  unsigned short* amps = (unsigned short*)d_ws;          // 128*10*2048*3 ushorts (~15.7 MB)
  float2* tw  = (float2*)(amps + (size_t)NS * 10 * TT * 3);
  float2* tw3 = tw + NFFT;                    // 876*4 float2 (~28 KB)
  float2* Hc  = tw3 + 4 * TW3_TOT;            // 20*4096 float2 (~655 KB)
  float2* Xs  = Hc + (size_t)NF * NFFT;       // 128*4096 float2 (~4.2 MB)
  unsigned int* binp = (unsigned int*)(Xs + (size_t)NS * NFFT);  // 128*10*512 dwords

  prep_kernel<<<20, 256, 0, stream>>>(tw, tw3, out);
  specf_kernel<<<NF + NS, 512, 0, stream>>>(x, ker, tw, tw3, Hc, Xs);
  convhil_kernel<<<NS * 10, 256, 0, stream>>>(Xs, Hc, tw, tw3, amps, binp);
  mi_kernel<<<640, 256, 0, stream>>>(amps, binp, out);
}